// Round 9
// baseline (472.018 us; speedup 1.0000x reference)
//
#include <hip/hip_runtime.h>
#include <math.h>

#define NN    320
#define CC    16
#define PP    262144
#define OSZ   360
#define HOSZ  180
#define BETA  4.4181248f
#define BETA2 19.519827f
#define PIW_OS 0.02617993878f                 // pi*W/OS = pi/120
#define RAD_PER 0.017453292519943295f         // 2*pi/360

// ---------- Kaiser-Bessel I0 (A&S 9.8.1 / 9.8.2, rel err ~2e-7) ----------
__device__ __forceinline__ float i0f(float x) {
  if (x < 3.75f) {
    float t = x * (1.0f / 3.75f); t *= t;
    return 1.0f + t*(3.5156229f + t*(3.0899424f + t*(1.2067492f +
           t*(0.2659732f + t*(0.0360768f + t*0.0045813f)))));
  } else {
    float t = 3.75f / x;
    float p = 0.39894228f + t*(0.01328592f + t*(0.00225319f + t*(-0.00157565f +
              t*(0.00916281f + t*(-0.02057706f + t*(0.02635537f +
              t*(-0.01647633f + t*0.00392377f)))))));
    return p * expf(x) * rsqrtf(x);
  }
}

// image-domain apodization a[i], i in [0,320)
__device__ __forceinline__ float apodf(int i) {
  float u = PIW_OS * (float)(i - 160);
  float t2 = BETA2 - u * u;
  float t = sqrtf(fmaxf(t2, 1e-12f));
  return t / sinhf(t);
}

// Sentinel: fill first 64 output floats with a marker value (diagnostic).
__global__ void sentinel_kernel(float* out, float v) {
  if (threadIdx.x < 64) out[threadIdx.x] = v;
}

// ---------------------------------------------------------------------------
// Literal-transcription DFT (dual-implemented r2/r4, delta-proven; unchanged).
// Pass 1: block=(c,q), q = ifftshifted padded row index. Full 360-pt DFT
// along x with exact integer-angle twiddle table. T1 complex, in d_out.
// ---------------------------------------------------------------------------
__global__ __launch_bounds__(384) void nufft_pass1(
    const float* __restrict__ imr, const float* __restrict__ imi,
    float2* __restrict__ T1) {
  int bid = blockIdx.x;
  int c = bid / OSZ;
  int q = bid - c * OSZ;
  int tid = threadIdx.x;

  __shared__ float2 srow[OSZ];
  __shared__ float2 tw[OSZ];

  int y = (q + 180) % OSZ - 20;               // source image row (may be OOR)
  bool rowz = (y < 0) || (y >= NN);
  float ay = rowz ? 0.0f : apodf(y) * (1.0f / 360.0f);
  const float* rr = imr + (size_t)(c * NN + (rowz ? 0 : y)) * NN;
  const float* ri = imi + (size_t)(c * NN + (rowz ? 0 : y)) * NN;

  for (int n = tid; n < OSZ; n += 384) {
    float sn, cs;
    sincosf(-RAD_PER * (float)n, &sn, &cs);
    tw[n] = make_float2(cs, sn);

    int x = (n + 180) % OSZ - 20;             // source image col (may be OOR)
    float2 v = make_float2(0.0f, 0.0f);
    if (!rowz && x >= 0 && x < NN) {
      float s = apodf(x) * ay;
      v = make_float2(rr[x] * s, ri[x] * s);
    }
    srow[n] = v;
  }
  __syncthreads();
  if (tid >= OSZ) return;
  int k = tid;

  float accr = 0.0f, acci = 0.0f;
  int m = 0;
  for (int n = 0; n < OSZ; ++n) {
    float2 v = srow[n];
    float2 w = tw[m];
    accr += v.x * w.x - v.y * w.y;
    acci += v.x * w.y + v.y * w.x;
    m += k; if (m >= OSZ) m -= OSZ;           // m = (k*n) mod 360, exact
  }
  T1[(c * OSZ + k) * OSZ + q] = make_float2(accr, acci);
}

// Pass 2: block=(c,kx). Full 360-pt DFT over q axis of T1[c][kx][*].
// Output needed downstream is only Re (weights are real, output is Re(kdata))
// -> store REAL-ONLY channel-last KGre[(ky*360+kx)*16 + c].
__global__ __launch_bounds__(384) void nufft_pass2(
    const float2* __restrict__ T1, float* __restrict__ KGre) {
  int bid = blockIdx.x;
  int c = bid / OSZ;
  int kx = bid - c * OSZ;
  int tid = threadIdx.x;

  __shared__ float2 srow[OSZ];
  __shared__ float2 tw[OSZ];

  const float2* src = T1 + (size_t)(c * OSZ + kx) * OSZ;
  for (int n = tid; n < OSZ; n += 384) {
    float sn, cs;
    sincosf(-RAD_PER * (float)n, &sn, &cs);
    tw[n] = make_float2(cs, sn);
    srow[n] = src[n];
  }
  __syncthreads();
  if (tid >= OSZ) return;
  int k = tid;

  float accr = 0.0f;
  int m = 0;
  for (int n = 0; n < OSZ; ++n) {
    float2 v = srow[n];
    float2 w = tw[m];
    accr += v.x * w.x - v.y * w.y;   // real part of v * w
    m += k; if (m >= OSZ) m -= OSZ;
  }
  KGre[((size_t)k * OSZ + kx) * CC + c] = accr;
}

// ---------------------------------------------------------------------------
// Gridder (round-6 independent implementation, real-only).
// One thread per (c,p), g = p*16 + c so the 16 lanes of a p gather the
// channel-contiguous 64B KGre cell coalesced.
// OUTPUT: float32 (C,P): out[c*P + p] = Re(kdata[c,p]).  (out_size=4,194,304)
// ---------------------------------------------------------------------------
__global__ __launch_bounds__(256) void grid_literal(
    const float* __restrict__ coord, const float* __restrict__ KGre,
    float* __restrict__ out) {
  int g = blockIdx.x * 256 + threadIdx.x;     // g = p*16 + c
  if (g >= PP * CC) return;
  int p = g >> 4;
  int c = g & 15;

  float posy = __fadd_rn(__fmul_rn(coord[2 * p],     1.125f), 180.0f);
  float posx = __fadd_rn(__fmul_rn(coord[2 * p + 1], 1.125f), 180.0f);
  float sty = ceilf(__fadd_rn(posy, -1.5f));
  float stx = ceilf(__fadd_rn(posx, -1.5f));

  float sr = 0.0f;
  for (int a = 0; a < 3; ++a) {
    float gy = sty + (float)a;
    float dy = posy - gy;
    float xfy = (2.0f * dy) / 3.0f;
    float argy = 1.0f - xfy * xfy;
    if (argy < 0.0f) argy = 0.0f;
    float wya = (fabsf(xfy) <= 1.0f) ? i0f(BETA * sqrtf(argy)) : 0.0f;

    int giy = (int)gy;
    giy = giy % OSZ; if (giy < 0) giy += OSZ;
    int ys = giy + HOSZ; if (ys >= OSZ) ys -= OSZ;   // fftshift remap

    for (int b = 0; b < 3; ++b) {
      float gx = stx + (float)b;
      float dx = posx - gx;
      float xfx = (2.0f * dx) / 3.0f;
      float argx = 1.0f - xfx * xfx;
      if (argx < 0.0f) argx = 0.0f;
      float wxb = (fabsf(xfx) <= 1.0f) ? i0f(BETA * sqrtf(argx)) : 0.0f;

      int gix = (int)gx;
      gix = gix % OSZ; if (gix < 0) gix += OSZ;
      int xs = gix + HOSZ; if (xs >= OSZ) xs -= OSZ;

      sr += (wya * wxb) * KGre[((size_t)ys * OSZ + xs) * CC + c];
    }
  }

  out[(size_t)c * PP + p] = sr;
}

extern "C" void kernel_launch(void* const* d_in, const int* in_sizes, int n_in,
                              void* d_out, int out_size, void* d_ws, size_t ws_size,
                              hipStream_t stream) {
  bool sizes_ok = (n_in >= 3) &&
                  (in_sizes[0] == CC * NN * NN) &&
                  (in_sizes[1] == CC * NN * NN) &&
                  (in_sizes[2] == PP * 2);
  if (!sizes_ok) {
    hipLaunchKernelGGL(sentinel_kernel, dim3(1), dim3(64), 0, stream,
                       (float*)d_out, 555.0f);
    return;
  }
  if (ws_size < (size_t)CC * OSZ * OSZ * sizeof(float)) {  // 8,294,400 B
    hipLaunchKernelGGL(sentinel_kernel, dim3(1), dim3(64), 0, stream,
                       (float*)d_out, 777.0f);
    return;
  }

  const float* imr   = (const float*)d_in[0];
  const float* imi   = (const float*)d_in[1];
  const float* coord = (const float*)d_in[2];

  // d_out = 4,194,304 float32 = 16.78 MB (real part of kdata, (C,P)).
  // T1 scratch (complex float2, 16.59 MB) fits in d_out, dead before
  // grid_literal overwrites all of d_out. KGre (real, 8.29 MB) in d_ws.
  float2* T1  = (float2*)d_out;
  float*  KGre = (float*)d_ws;

  hipLaunchKernelGGL(nufft_pass1, dim3(CC * OSZ), dim3(384), 0, stream, imr, imi, T1);
  hipLaunchKernelGGL(nufft_pass2, dim3(CC * OSZ), dim3(384), 0, stream, T1, KGre);
  hipLaunchKernelGGL(grid_literal, dim3((PP * CC) / 256), dim3(256), 0, stream,
                     coord, KGre, (float*)d_out);
}

// Round 10
// 125.255 us; speedup vs baseline: 3.7684x; 3.7684x over previous
//
#include <hip/hip_runtime.h>
#include <math.h>

#define NN    320
#define CC    16
#define PP    262144
#define OSZ   360
#define HOSZ  180
#define BETA  4.4180974f
#define BETA2 19.5195850f
#define PIW_OS 0.02617993878f                 // pi*W/OS = pi/120
#define RAD_PER 0.017453292519943295f         // 2*pi/360
#define QT 8                                  // q-rows per pass1 block

// ---------- Kaiser-Bessel I0 (A&S 9.8.1 / 9.8.2, rel err ~2e-7) ----------
__device__ __forceinline__ float i0f(float x) {
  if (x < 3.75f) {
    float t = x * (1.0f / 3.75f); t *= t;
    return 1.0f + t*(3.5156229f + t*(3.0899424f + t*(1.2067492f +
           t*(0.2659732f + t*(0.0360768f + t*0.0045813f)))));
  } else {
    float t = 3.75f / x;
    float p = 0.39894228f + t*(0.01328592f + t*(0.00225319f + t*(-0.00157565f +
              t*(0.00916281f + t*(-0.02057706f + t*(0.02635537f +
              t*(-0.01647633f + t*0.00392377f)))))));
    return p * expf(x) * rsqrtf(x);
  }
}

// image-domain apodization a[i], i in [0,320)
__device__ __forceinline__ float apodf(int i) {
  float u = PIW_OS * (float)(i - 160);
  float t2 = BETA2 - u * u;
  float t = sqrtf(fmaxf(t2, 1e-12f));
  return t / sinhf(t);
}

// Sentinel: fill first 64 output floats with a marker value (diagnostic).
__global__ void sentinel_kernel(float* out, float v) {
  if (threadIdx.x < 64) out[threadIdx.x] = v;
}

// ---------------------------------------------------------------------------
// Two-stage Cooley-Tukey 360-pt DFT: 360 = 18 x 20, n = 20*n1 + n2.
//   stage1: A[k1][n2] = sum_{n1<18} x[20*n1+n2] * tw[(20*n1*k1) % 360]
//   stage2: X[k]      = sum_{n2<20} A[k%18][n2] * tw[(n2*k) % 360]
// Exact: 20*n1*k1 === 20*n1*k (mod 360) since 20*18 = 360. Twiddle table
// identical to the literal DFT's; only summation order changes (fp32 drift
// well under threshold). A padded to stride 21 to break bank conflicts.
// ---------------------------------------------------------------------------

// Pass 1: block = (c, 8-row q-tile). Apodize+pad+ifftshift, FFT along x,
// write T1[c][k][q0..q0+7] as one 64B store per k.
__global__ __launch_bounds__(384) void nufft_pass1(
    const float* __restrict__ imr, const float* __restrict__ imi,
    float2* __restrict__ T1) {
  int bid = blockIdx.x;
  int c  = bid / (OSZ / QT);                 // 45 tiles per channel
  int qt = bid - c * (OSZ / QT);
  int q0 = qt * QT;
  int tid = threadIdx.x;

  __shared__ float2 tw[OSZ];
  __shared__ float2 srow[OSZ];
  __shared__ float2 A[18 * 21];
  __shared__ float  apodL[NN];

  for (int n = tid; n < OSZ; n += 384) {
    float sn, cs; sincosf(-RAD_PER * (float)n, &sn, &cs);
    tw[n] = make_float2(cs, sn);
  }
  for (int i = tid; i < NN; i += 384) apodL[i] = apodf(i);

  // fully-zero q-tile fast path (q in [160,200) are pad rows)
  if (q0 >= 160 && q0 + QT <= 200) {
    if (tid < OSZ) {
      float4 z = make_float4(0.f, 0.f, 0.f, 0.f);
      float4* dst = (float4*)&T1[((size_t)(c * OSZ + tid)) * OSZ + q0];
      dst[0] = z; dst[1] = z; dst[2] = z; dst[3] = z;
    }
    return;
  }

  float2 X[QT];
  const float inv360 = 1.0f / 360.0f;

  for (int r = 0; r < QT; ++r) {
    int q = q0 + r;
    int y = (q + 180) % OSZ - 20;            // source image row (may be OOR)
    bool rowz = (y < 0) || (y >= NN);
    __syncthreads();                         // prev iter's A/srow reads done
    float ay = rowz ? 0.0f : apodL[y] * inv360;
    const float* rr = imr + (size_t)(c * NN + (rowz ? 0 : y)) * NN;
    const float* ri = imi + (size_t)(c * NN + (rowz ? 0 : y)) * NN;
    for (int n = tid; n < OSZ; n += 384) {
      int x = (n + 180) % OSZ - 20;
      float2 v = make_float2(0.0f, 0.0f);
      if (!rowz && x >= 0 && x < NN) {
        float s = apodL[x] * ay;
        v = make_float2(rr[x] * s, ri[x] * s);
      }
      srow[n] = v;
    }
    __syncthreads();
    if (tid < OSZ) {                          // stage 1: 18-pt DFTs
      int k1 = tid / 20, n2 = tid - k1 * 20;
      int dm = 20 * k1;                       // <= 340, single-wrap safe
      float ar = 0.f, ai = 0.f; int m = 0, idx = n2;
      #pragma unroll 6
      for (int n1 = 0; n1 < 18; ++n1) {
        float2 v = srow[idx]; float2 w = tw[m];
        ar = fmaf(v.x, w.x, ar); ar = fmaf(-v.y, w.y, ar);
        ai = fmaf(v.x, w.y, ai); ai = fmaf( v.y, w.x, ai);
        idx += 20; m += dm; if (m >= OSZ) m -= OSZ;
      }
      A[k1 * 21 + n2] = make_float2(ar, ai);
    }
    __syncthreads();
    if (tid < OSZ) {                          // stage 2: 20-pt DFTs + twiddle
      int k = tid; int base = (k % 18) * 21;
      float xr = 0.f, xi = 0.f; int m = 0;
      #pragma unroll 5
      for (int n2 = 0; n2 < 20; ++n2) {
        float2 a = A[base + n2]; float2 w = tw[m];
        xr = fmaf(a.x, w.x, xr); xr = fmaf(-a.y, w.y, xr);
        xi = fmaf(a.x, w.y, xi); xi = fmaf( a.y, w.x, xi);
        m += k; if (m >= OSZ) m -= OSZ;
      }
      X[r] = make_float2(xr, xi);
    }
  }
  if (tid < OSZ) {
    float4* dst = (float4*)&T1[((size_t)(c * OSZ + tid)) * OSZ + q0];
    dst[0] = make_float4(X[0].x, X[0].y, X[1].x, X[1].y);
    dst[1] = make_float4(X[2].x, X[2].y, X[3].x, X[3].y);
    dst[2] = make_float4(X[4].x, X[4].y, X[5].x, X[5].y);
    dst[3] = make_float4(X[6].x, X[6].y, X[7].x, X[7].y);
  }
}

// Pass 2: block = (kx, 8-channel group). FFT over q axis of T1[c][kx][*],
// keep real part only; write KGre[(k*360+kx)*16 + ch0..ch0+7] (32B store).
__global__ __launch_bounds__(384) void nufft_pass2(
    const float2* __restrict__ T1, float* __restrict__ KGre) {
  int bid = blockIdx.x;
  int kx  = bid >> 1;
  int ch0 = (bid & 1) * 8;
  int tid = threadIdx.x;

  __shared__ float2 tw[OSZ];
  __shared__ float2 srow[OSZ];
  __shared__ float2 A[18 * 21];

  for (int n = tid; n < OSZ; n += 384) {
    float sn, cs; sincosf(-RAD_PER * (float)n, &sn, &cs);
    tw[n] = make_float2(cs, sn);
  }

  float kg[8];
  for (int ci = 0; ci < 8; ++ci) {
    int c = ch0 + ci;
    __syncthreads();
    const float2* src = T1 + ((size_t)(c * OSZ + kx)) * OSZ;
    for (int n = tid; n < OSZ; n += 384) srow[n] = src[n];
    __syncthreads();
    if (tid < OSZ) {                          // stage 1 (complex)
      int k1 = tid / 20, n2 = tid - k1 * 20;
      int dm = 20 * k1;
      float ar = 0.f, ai = 0.f; int m = 0, idx = n2;
      #pragma unroll 6
      for (int n1 = 0; n1 < 18; ++n1) {
        float2 v = srow[idx]; float2 w = tw[m];
        ar = fmaf(v.x, w.x, ar); ar = fmaf(-v.y, w.y, ar);
        ai = fmaf(v.x, w.y, ai); ai = fmaf( v.y, w.x, ai);
        idx += 20; m += dm; if (m >= OSZ) m -= OSZ;
      }
      A[k1 * 21 + n2] = make_float2(ar, ai);
    }
    __syncthreads();
    if (tid < OSZ) {                          // stage 2, real part only
      int k = tid; int base = (k % 18) * 21;
      float xr = 0.f; int m = 0;
      #pragma unroll 5
      for (int n2 = 0; n2 < 20; ++n2) {
        float2 a = A[base + n2]; float2 w = tw[m];
        xr = fmaf(a.x, w.x, xr); xr = fmaf(-a.y, w.y, xr);
        m += k; if (m >= OSZ) m -= OSZ;
      }
      kg[ci] = xr;
    }
  }
  if (tid < OSZ) {
    float4* dst = (float4*)&KGre[((size_t)tid * OSZ + kx) * CC + ch0];
    dst[0] = make_float4(kg[0], kg[1], kg[2], kg[3]);
    dst[1] = make_float4(kg[4], kg[5], kg[6], kg[7]);
  }
}

// ---------------------------------------------------------------------------
// Gridder (round-9 passing version, unchanged). One thread per (c,p).
// OUTPUT: float32 (C,P): out[c*P + p] = Re(kdata[c,p]).
// ---------------------------------------------------------------------------
__global__ __launch_bounds__(256) void grid_literal(
    const float* __restrict__ coord, const float* __restrict__ KGre,
    float* __restrict__ out) {
  int g = blockIdx.x * 256 + threadIdx.x;     // g = p*16 + c
  if (g >= PP * CC) return;
  int p = g >> 4;
  int c = g & 15;

  float posy = __fadd_rn(__fmul_rn(coord[2 * p],     1.125f), 180.0f);
  float posx = __fadd_rn(__fmul_rn(coord[2 * p + 1], 1.125f), 180.0f);
  float sty = ceilf(__fadd_rn(posy, -1.5f));
  float stx = ceilf(__fadd_rn(posx, -1.5f));

  float sr = 0.0f;
  for (int a = 0; a < 3; ++a) {
    float gy = sty + (float)a;
    float dy = posy - gy;
    float xfy = (2.0f * dy) / 3.0f;
    float argy = 1.0f - xfy * xfy;
    if (argy < 0.0f) argy = 0.0f;
    float wya = (fabsf(xfy) <= 1.0f) ? i0f(BETA * sqrtf(argy)) : 0.0f;

    int giy = (int)gy;
    giy = giy % OSZ; if (giy < 0) giy += OSZ;
    int ys = giy + HOSZ; if (ys >= OSZ) ys -= OSZ;   // fftshift remap

    for (int b = 0; b < 3; ++b) {
      float gx = stx + (float)b;
      float dx = posx - gx;
      float xfx = (2.0f * dx) / 3.0f;
      float argx = 1.0f - xfx * xfx;
      if (argx < 0.0f) argx = 0.0f;
      float wxb = (fabsf(xfx) <= 1.0f) ? i0f(BETA * sqrtf(argx)) : 0.0f;

      int gix = (int)gx;
      gix = gix % OSZ; if (gix < 0) gix += OSZ;
      int xs = gix + HOSZ; if (xs >= OSZ) xs -= OSZ;

      sr += (wya * wxb) * KGre[((size_t)ys * OSZ + xs) * CC + c];
    }
  }

  out[(size_t)c * PP + p] = sr;
}

extern "C" void kernel_launch(void* const* d_in, const int* in_sizes, int n_in,
                              void* d_out, int out_size, void* d_ws, size_t ws_size,
                              hipStream_t stream) {
  bool sizes_ok = (n_in >= 3) &&
                  (in_sizes[0] == CC * NN * NN) &&
                  (in_sizes[1] == CC * NN * NN) &&
                  (in_sizes[2] == PP * 2);
  if (!sizes_ok) {
    hipLaunchKernelGGL(sentinel_kernel, dim3(1), dim3(64), 0, stream,
                       (float*)d_out, 555.0f);
    return;
  }
  if (ws_size < (size_t)CC * OSZ * OSZ * sizeof(float)) {  // 8,294,400 B
    hipLaunchKernelGGL(sentinel_kernel, dim3(1), dim3(64), 0, stream,
                       (float*)d_out, 777.0f);
    return;
  }

  const float* imr   = (const float*)d_in[0];
  const float* imi   = (const float*)d_in[1];
  const float* coord = (const float*)d_in[2];

  // d_out = 4,194,304 float32 = 16.78 MB (real part of kdata, (C,P)).
  // T1 scratch (complex float2, 16.59 MB) fits in d_out, dead before
  // grid_literal overwrites all of d_out. KGre (real, 8.29 MB) in d_ws.
  float2* T1   = (float2*)d_out;
  float*  KGre = (float*)d_ws;

  hipLaunchKernelGGL(nufft_pass1, dim3(CC * (OSZ / QT)), dim3(384), 0, stream,
                     imr, imi, T1);
  hipLaunchKernelGGL(nufft_pass2, dim3(OSZ * 2), dim3(384), 0, stream,
                     T1, KGre);
  hipLaunchKernelGGL(grid_literal, dim3((PP * CC) / 256), dim3(256), 0, stream,
                     coord, KGre, (float*)d_out);
}

// Round 11
// 106.396 us; speedup vs baseline: 4.4364x; 1.1773x over previous
//
#include <hip/hip_runtime.h>
#include <math.h>

#define NN    320
#define CC    16
#define PP    262144
#define OSZ   360
#define HOSZ  180
#define BETA  4.4180974f
#define BETA2 19.5195850f
#define PIW_OS 0.02617993878f                 // pi*W/OS = pi/120
#define RAD_PER 0.017453292519943295f         // 2*pi/360
#define QT 8                                  // q-rows per pass1 block

// ---------- Kaiser-Bessel I0 (A&S 9.8.1 / 9.8.2, rel err ~2e-7) ----------
__device__ __forceinline__ float i0f(float x) {
  if (x < 3.75f) {
    float t = x * (1.0f / 3.75f); t *= t;
    return 1.0f + t*(3.5156229f + t*(3.0899424f + t*(1.2067492f +
           t*(0.2659732f + t*(0.0360768f + t*0.0045813f)))));
  } else {
    float t = 3.75f / x;
    float p = 0.39894228f + t*(0.01328592f + t*(0.00225319f + t*(-0.00157565f +
              t*(0.00916281f + t*(-0.02057706f + t*(0.02635537f +
              t*(-0.01647633f + t*0.00392377f)))))));
    return p * expf(x) * rsqrtf(x);
  }
}

// image-domain apodization a[i], i in [0,320)
__device__ __forceinline__ float apodf(int i) {
  float u = PIW_OS * (float)(i - 160);
  float t2 = BETA2 - u * u;
  float t = sqrtf(fmaxf(t2, 1e-12f));
  return t / sinhf(t);
}

// Sentinel: fill first 64 output floats with a marker value (diagnostic).
__global__ void sentinel_kernel(float* out, float v) {
  if (threadIdx.x < 64) out[threadIdx.x] = v;
}

// ---------------------------------------------------------------------------
// Two-stage Cooley-Tukey 360-pt DFT: 360 = 18 x 20 (unchanged from round 10).
// ---------------------------------------------------------------------------

// Pass 1: block = (c, 8-row q-tile). Apodize+pad+ifftshift, FFT along x,
// write T1[c][k][q0..q0+7] as one 64B store per k.
__global__ __launch_bounds__(384) void nufft_pass1(
    const float* __restrict__ imr, const float* __restrict__ imi,
    float2* __restrict__ T1) {
  int bid = blockIdx.x;
  int c  = bid / (OSZ / QT);                 // 45 tiles per channel
  int qt = bid - c * (OSZ / QT);
  int q0 = qt * QT;
  int tid = threadIdx.x;

  __shared__ float2 tw[OSZ];
  __shared__ float2 srow[OSZ];
  __shared__ float2 A[18 * 21];
  __shared__ float  apodL[NN];

  for (int n = tid; n < OSZ; n += 384) {
    float sn, cs; sincosf(-RAD_PER * (float)n, &sn, &cs);
    tw[n] = make_float2(cs, sn);
  }
  for (int i = tid; i < NN; i += 384) apodL[i] = apodf(i);

  // fully-zero q-tile fast path (q in [160,200) are pad rows)
  if (q0 >= 160 && q0 + QT <= 200) {
    if (tid < OSZ) {
      float4 z = make_float4(0.f, 0.f, 0.f, 0.f);
      float4* dst = (float4*)&T1[((size_t)(c * OSZ + tid)) * OSZ + q0];
      dst[0] = z; dst[1] = z; dst[2] = z; dst[3] = z;
    }
    return;
  }

  float2 X[QT];
  const float inv360 = 1.0f / 360.0f;

  for (int r = 0; r < QT; ++r) {
    int q = q0 + r;
    int y = (q + 180) % OSZ - 20;            // source image row (may be OOR)
    bool rowz = (y < 0) || (y >= NN);
    __syncthreads();                         // prev iter's A/srow reads done
    float ay = rowz ? 0.0f : apodL[y] * inv360;
    const float* rr = imr + (size_t)(c * NN + (rowz ? 0 : y)) * NN;
    const float* ri = imi + (size_t)(c * NN + (rowz ? 0 : y)) * NN;
    for (int n = tid; n < OSZ; n += 384) {
      int x = (n + 180) % OSZ - 20;
      float2 v = make_float2(0.0f, 0.0f);
      if (!rowz && x >= 0 && x < NN) {
        float s = apodL[x] * ay;
        v = make_float2(rr[x] * s, ri[x] * s);
      }
      srow[n] = v;
    }
    __syncthreads();
    if (tid < OSZ) {                          // stage 1: 18-pt DFTs
      int k1 = tid / 20, n2 = tid - k1 * 20;
      int dm = 20 * k1;                       // <= 340, single-wrap safe
      float ar = 0.f, ai = 0.f; int m = 0, idx = n2;
      #pragma unroll 6
      for (int n1 = 0; n1 < 18; ++n1) {
        float2 v = srow[idx]; float2 w = tw[m];
        ar = fmaf(v.x, w.x, ar); ar = fmaf(-v.y, w.y, ar);
        ai = fmaf(v.x, w.y, ai); ai = fmaf( v.y, w.x, ai);
        idx += 20; m += dm; if (m >= OSZ) m -= OSZ;
      }
      A[k1 * 21 + n2] = make_float2(ar, ai);
    }
    __syncthreads();
    if (tid < OSZ) {                          // stage 2: 20-pt DFTs + twiddle
      int k = tid; int base = (k % 18) * 21;
      float xr = 0.f, xi = 0.f; int m = 0;
      #pragma unroll 5
      for (int n2 = 0; n2 < 20; ++n2) {
        float2 a = A[base + n2]; float2 w = tw[m];
        xr = fmaf(a.x, w.x, xr); xr = fmaf(-a.y, w.y, xr);
        xi = fmaf(a.x, w.y, xi); xi = fmaf( a.y, w.x, xi);
        m += k; if (m >= OSZ) m -= OSZ;
      }
      X[r] = make_float2(xr, xi);
    }
  }
  if (tid < OSZ) {
    float4* dst = (float4*)&T1[((size_t)(c * OSZ + tid)) * OSZ + q0];
    dst[0] = make_float4(X[0].x, X[0].y, X[1].x, X[1].y);
    dst[1] = make_float4(X[2].x, X[2].y, X[3].x, X[3].y);
    dst[2] = make_float4(X[4].x, X[4].y, X[5].x, X[5].y);
    dst[3] = make_float4(X[6].x, X[6].y, X[7].x, X[7].y);
  }
}

// Pass 2: block = (kx, 8-channel group). FFT over q axis of T1[c][kx][*],
// keep real part only; write KGre[(k*360+kx)*16 + ch0..ch0+7] (32B store).
__global__ __launch_bounds__(384) void nufft_pass2(
    const float2* __restrict__ T1, float* __restrict__ KGre) {
  int bid = blockIdx.x;
  int kx  = bid >> 1;
  int ch0 = (bid & 1) * 8;
  int tid = threadIdx.x;

  __shared__ float2 tw[OSZ];
  __shared__ float2 srow[OSZ];
  __shared__ float2 A[18 * 21];

  for (int n = tid; n < OSZ; n += 384) {
    float sn, cs; sincosf(-RAD_PER * (float)n, &sn, &cs);
    tw[n] = make_float2(cs, sn);
  }

  float kg[8];
  for (int ci = 0; ci < 8; ++ci) {
    int c = ch0 + ci;
    __syncthreads();
    const float2* src = T1 + ((size_t)(c * OSZ + kx)) * OSZ;
    for (int n = tid; n < OSZ; n += 384) srow[n] = src[n];
    __syncthreads();
    if (tid < OSZ) {                          // stage 1 (complex)
      int k1 = tid / 20, n2 = tid - k1 * 20;
      int dm = 20 * k1;
      float ar = 0.f, ai = 0.f; int m = 0, idx = n2;
      #pragma unroll 6
      for (int n1 = 0; n1 < 18; ++n1) {
        float2 v = srow[idx]; float2 w = tw[m];
        ar = fmaf(v.x, w.x, ar); ar = fmaf(-v.y, w.y, ar);
        ai = fmaf(v.x, w.y, ai); ai = fmaf( v.y, w.x, ai);
        idx += 20; m += dm; if (m >= OSZ) m -= OSZ;
      }
      A[k1 * 21 + n2] = make_float2(ar, ai);
    }
    __syncthreads();
    if (tid < OSZ) {                          // stage 2, real part only
      int k = tid; int base = (k % 18) * 21;
      float xr = 0.f; int m = 0;
      #pragma unroll 5
      for (int n2 = 0; n2 < 20; ++n2) {
        float2 a = A[base + n2]; float2 w = tw[m];
        xr = fmaf(a.x, w.x, xr); xr = fmaf(-a.y, w.y, xr);
        m += k; if (m >= OSZ) m -= OSZ;
      }
      kg[ci] = xr;
    }
  }
  if (tid < OSZ) {
    float4* dst = (float4*)&KGre[((size_t)tid * OSZ + kx) * CC + ch0];
    dst[0] = make_float4(kg[0], kg[1], kg[2], kg[3]);
    dst[1] = make_float4(kg[4], kg[5], kg[6], kg[7]);
  }
}

// ---------------------------------------------------------------------------
// Gridder v2: ONE THREAD PER POINT p, all 16 channels.
// Weights/indices computed once per p (was 16x redundant -> VALU-bound).
// Per tap: 4 coalesced float4 loads of the channel-contiguous 64B KGre cell.
// OUTPUT: float32 (C,P): out[c*P + p] = Re(kdata[c,p]).
// ---------------------------------------------------------------------------
__global__ __launch_bounds__(256) void grid_points(
    const float* __restrict__ coord, const float* __restrict__ KGre,
    float* __restrict__ out) {
  int p = blockIdx.x * 256 + threadIdx.x;
  if (p >= PP) return;

  float2 cv = ((const float2*)coord)[p];
  float posy = __fadd_rn(__fmul_rn(cv.x, 1.125f), 180.0f);
  float posx = __fadd_rn(__fmul_rn(cv.y, 1.125f), 180.0f);
  float sty = ceilf(__fadd_rn(posy, -1.5f));
  float stx = ceilf(__fadd_rn(posx, -1.5f));

  float wy[3], wx[3];
  int jy[3], jx[3];
  #pragma unroll
  for (int r = 0; r < 3; ++r) {
    float gy = sty + (float)r;
    float dy = posy - gy;
    float xf = (2.0f * dy) / 3.0f;
    float arg = 1.0f - xf * xf;
    if (arg < 0.0f) arg = 0.0f;
    wy[r] = (fabsf(xf) <= 1.0f) ? i0f(BETA * sqrtf(arg)) : 0.0f;
    int gi = (int)gy;
    gi = gi % OSZ; if (gi < 0) gi += OSZ;
    gi += HOSZ; if (gi >= OSZ) gi -= OSZ;     // fftshift remap
    jy[r] = gi;

    float gx = stx + (float)r;
    float dx = posx - gx;
    xf = (2.0f * dx) / 3.0f;
    arg = 1.0f - xf * xf;
    if (arg < 0.0f) arg = 0.0f;
    wx[r] = (fabsf(xf) <= 1.0f) ? i0f(BETA * sqrtf(arg)) : 0.0f;
    gi = (int)gx;
    gi = gi % OSZ; if (gi < 0) gi += OSZ;
    gi += HOSZ; if (gi >= OSZ) gi -= OSZ;
    jx[r] = gi;
  }

  float acc[CC];
  #pragma unroll
  for (int c = 0; c < CC; ++c) acc[c] = 0.0f;

  #pragma unroll
  for (int a = 0; a < 3; ++a) {
    #pragma unroll
    for (int b = 0; b < 3; ++b) {
      float w = wy[a] * wx[b];
      const float4* g4 = (const float4*)(KGre + ((size_t)jy[a] * OSZ + jx[b]) * CC);
      #pragma unroll
      for (int h = 0; h < 4; ++h) {
        float4 v = g4[h];
        acc[4*h+0] = fmaf(w, v.x, acc[4*h+0]);
        acc[4*h+1] = fmaf(w, v.y, acc[4*h+1]);
        acc[4*h+2] = fmaf(w, v.z, acc[4*h+2]);
        acc[4*h+3] = fmaf(w, v.w, acc[4*h+3]);
      }
    }
  }

  #pragma unroll
  for (int c = 0; c < CC; ++c) out[(size_t)c * PP + p] = acc[c];
}

extern "C" void kernel_launch(void* const* d_in, const int* in_sizes, int n_in,
                              void* d_out, int out_size, void* d_ws, size_t ws_size,
                              hipStream_t stream) {
  bool sizes_ok = (n_in >= 3) &&
                  (in_sizes[0] == CC * NN * NN) &&
                  (in_sizes[1] == CC * NN * NN) &&
                  (in_sizes[2] == PP * 2);
  if (!sizes_ok) {
    hipLaunchKernelGGL(sentinel_kernel, dim3(1), dim3(64), 0, stream,
                       (float*)d_out, 555.0f);
    return;
  }
  if (ws_size < (size_t)CC * OSZ * OSZ * sizeof(float)) {  // 8,294,400 B
    hipLaunchKernelGGL(sentinel_kernel, dim3(1), dim3(64), 0, stream,
                       (float*)d_out, 777.0f);
    return;
  }

  const float* imr   = (const float*)d_in[0];
  const float* imi   = (const float*)d_in[1];
  const float* coord = (const float*)d_in[2];

  // d_out = 4,194,304 float32 = 16.78 MB (real part of kdata, (C,P)).
  // T1 scratch (complex float2, 16.59 MB) fits in d_out, dead before
  // grid_points overwrites all of d_out. KGre (real, 8.29 MB) in d_ws.
  float2* T1   = (float2*)d_out;
  float*  KGre = (float*)d_ws;

  hipLaunchKernelGGL(nufft_pass1, dim3(CC * (OSZ / QT)), dim3(384), 0, stream,
                     imr, imi, T1);
  hipLaunchKernelGGL(nufft_pass2, dim3(OSZ * 2), dim3(384), 0, stream,
                     T1, KGre);
  hipLaunchKernelGGL(grid_points, dim3(PP / 256), dim3(256), 0, stream,
                     coord, KGre, (float*)d_out);
}

// Round 12
// 95.564 us; speedup vs baseline: 4.9393x; 1.1134x over previous
//
#include <hip/hip_runtime.h>
#include <math.h>

#define NN    320
#define CC    16
#define PP    262144
#define OSZ   360
#define HOSZ  180
#define BETA  4.4180974f
#define BETA2 19.5195850f
#define PIW_OS 0.02617993878f                 // pi*W/OS = pi/120
#define RAD_PER 0.017453292519943295f         // 2*pi/360
#define QT 8                                  // q-rows per pass1 block

// ---------- Kaiser-Bessel I0 (A&S 9.8.1 / 9.8.2, rel err ~2e-7) ----------
__device__ __forceinline__ float i0f(float x) {
  if (x < 3.75f) {
    float t = x * (1.0f / 3.75f); t *= t;
    return 1.0f + t*(3.5156229f + t*(3.0899424f + t*(1.2067492f +
           t*(0.2659732f + t*(0.0360768f + t*0.0045813f)))));
  } else {
    float t = 3.75f / x;
    float p = 0.39894228f + t*(0.01328592f + t*(0.00225319f + t*(-0.00157565f +
              t*(0.00916281f + t*(-0.02057706f + t*(0.02635537f +
              t*(-0.01647633f + t*0.00392377f)))))));
    return p * expf(x) * rsqrtf(x);
  }
}

// image-domain apodization a[i], i in [0,320)
__device__ __forceinline__ float apodf(int i) {
  float u = PIW_OS * (float)(i - 160);
  float t2 = BETA2 - u * u;
  float t = sqrtf(fmaxf(t2, 1e-12f));
  return t / sinhf(t);
}

// Sentinel: fill first 64 output floats with a marker value (diagnostic).
__global__ void sentinel_kernel(float* out, float v) {
  if (threadIdx.x < 64) out[threadIdx.x] = v;
}

// ---------------------------------------------------------------------------
// Two-stage Cooley-Tukey 360 = 18 x 20, batched 8 rows per barrier phase.
//   stage1: A[k1][n2] = sum_{n1} x[20*n1+n2] * tw[(20*n1*k1)%360]
//           n1 = 8,9 correspond to pad band n in [160,200) -> exact zeros,
//           skipped at compile time (bit-exact: skipping +0.0 terms).
//   stage2: X[k] = sum_{n2<20} A[k%18][n2] * tw[(n2*k)%360]
// ---------------------------------------------------------------------------

// Pass 1: block = (c, 8-row q-tile). 3 barriers per block (was 24).
__global__ __launch_bounds__(384) void nufft_pass1(
    const float* __restrict__ imr, const float* __restrict__ imi,
    float2* __restrict__ T1) {
  int bid = blockIdx.x;
  int c  = bid / (OSZ / QT);                 // 45 tiles per channel
  int qt = bid - c * (OSZ / QT);
  int q0 = qt * QT;
  int tid = threadIdx.x;

  __shared__ float2 tw[OSZ];
  __shared__ float  apodL[NN];
  __shared__ float2 srow[QT][OSZ];
  __shared__ float2 A[QT][18 * 21];

  for (int n = tid; n < OSZ; n += 384) {
    float sn, cs; sincosf(-RAD_PER * (float)n, &sn, &cs);
    tw[n] = make_float2(cs, sn);
  }
  for (int i = tid; i < NN; i += 384) apodL[i] = apodf(i);

  // fully-zero q-tile fast path (q in [160,200) are pad rows)
  if (q0 >= 160 && q0 + QT <= 200) {
    if (tid < OSZ) {
      float4 z = make_float4(0.f, 0.f, 0.f, 0.f);
      float4* dst = (float4*)&T1[((size_t)(c * OSZ + tid)) * OSZ + q0];
      dst[0] = z; dst[1] = z; dst[2] = z; dst[3] = z;
    }
    return;
  }
  __syncthreads();                            // apodL ready

  // load all 8 apodized/padded/ifftshifted rows
  const float inv360 = 1.0f / 360.0f;
  for (int i = tid; i < QT * OSZ; i += 384) {
    int r = i / OSZ, n = i - r * OSZ;
    int q = q0 + r;
    int y = (q + 180) % OSZ - 20;
    int x = (n + 180) % OSZ - 20;
    float2 v = make_float2(0.0f, 0.0f);
    if (y >= 0 && y < NN && x >= 0 && x < NN) {
      float s = apodL[x] * (apodL[y] * inv360);
      size_t o = (size_t)(c * NN + y) * NN + x;
      v = make_float2(imr[o] * s, imi[o] * s);
    }
    srow[r][n] = v;
  }
  __syncthreads();

  if (tid < OSZ) {                            // stage 1, all 8 rows
    int k1 = tid / 20, n2 = tid - k1 * 20;
    int dm = 20 * k1;                         // <= 340, single-wrap safe
    float ar[QT], ai[QT];
    #pragma unroll
    for (int r = 0; r < QT; ++r) { ar[r] = 0.f; ai[r] = 0.f; }
    int m = 0, idx = n2;
    #pragma unroll
    for (int n1 = 0; n1 < 18; ++n1) {
      if (n1 != 8 && n1 != 9) {               // n1=8,9: pad band, exact zeros
        float2 w = tw[m];
        #pragma unroll
        for (int r = 0; r < QT; ++r) {
          float2 v = srow[r][idx];
          ar[r] = fmaf(v.x, w.x, ar[r]); ar[r] = fmaf(-v.y, w.y, ar[r]);
          ai[r] = fmaf(v.x, w.y, ai[r]); ai[r] = fmaf( v.y, w.x, ai[r]);
        }
      }
      idx += 20; m += dm; if (m >= OSZ) m -= OSZ;
    }
    #pragma unroll
    for (int r = 0; r < QT; ++r) A[r][k1 * 21 + n2] = make_float2(ar[r], ai[r]);
  }
  __syncthreads();

  if (tid < OSZ) {                            // stage 2, all 8 rows
    int k = tid; int base = (k % 18) * 21;
    float xr[QT], xi[QT];
    #pragma unroll
    for (int r = 0; r < QT; ++r) { xr[r] = 0.f; xi[r] = 0.f; }
    int m = 0;
    #pragma unroll
    for (int n2 = 0; n2 < 20; ++n2) {
      float2 w = tw[m];
      #pragma unroll
      for (int r = 0; r < QT; ++r) {
        float2 a = A[r][base + n2];
        xr[r] = fmaf(a.x, w.x, xr[r]); xr[r] = fmaf(-a.y, w.y, xr[r]);
        xi[r] = fmaf(a.x, w.y, xi[r]); xi[r] = fmaf( a.y, w.x, xi[r]);
      }
      m += k; if (m >= OSZ) m -= OSZ;
    }
    float4* dst = (float4*)&T1[((size_t)(c * OSZ + tid)) * OSZ + q0];
    dst[0] = make_float4(xr[0], xi[0], xr[1], xi[1]);
    dst[1] = make_float4(xr[2], xi[2], xr[3], xi[3]);
    dst[2] = make_float4(xr[4], xi[4], xr[5], xi[5]);
    dst[3] = make_float4(xr[6], xi[6], xr[7], xi[7]);
  }
}

// Pass 2: block = (kx, 8-channel group). 2 barriers per block.
// Writes KGre PRE-FFTSHIFTED: KGs[(k+180)%360][(kx+180)%360][c] = Re F[k][kx].
__global__ __launch_bounds__(384) void nufft_pass2(
    const float2* __restrict__ T1, float* __restrict__ KGs) {
  int bid = blockIdx.x;
  int kx  = bid >> 1;
  int ch0 = (bid & 1) * 8;
  int tid = threadIdx.x;

  __shared__ float2 tw[OSZ];
  __shared__ float2 srow[8][OSZ];
  __shared__ float2 A[8][18 * 21];

  for (int n = tid; n < OSZ; n += 384) {
    float sn, cs; sincosf(-RAD_PER * (float)n, &sn, &cs);
    tw[n] = make_float2(cs, sn);
  }
  // load 8 channels' q-columns (T1 rows are zero for q in [160,200): skip read)
  for (int i = tid; i < 8 * OSZ; i += 384) {
    int ci = i / OSZ, n = i - ci * OSZ;
    float2 v = make_float2(0.0f, 0.0f);
    if (n < 160 || n >= 200)
      v = T1[((size_t)((ch0 + ci) * OSZ + kx)) * OSZ + n];
    srow[ci][n] = v;
  }
  __syncthreads();

  if (tid < OSZ) {                            // stage 1, all 8 channels
    int k1 = tid / 20, n2 = tid - k1 * 20;
    int dm = 20 * k1;
    float ar[8], ai[8];
    #pragma unroll
    for (int r = 0; r < 8; ++r) { ar[r] = 0.f; ai[r] = 0.f; }
    int m = 0, idx = n2;
    #pragma unroll
    for (int n1 = 0; n1 < 18; ++n1) {
      if (n1 != 8 && n1 != 9) {               // q pad band, exact zeros
        float2 w = tw[m];
        #pragma unroll
        for (int r = 0; r < 8; ++r) {
          float2 v = srow[r][idx];
          ar[r] = fmaf(v.x, w.x, ar[r]); ar[r] = fmaf(-v.y, w.y, ar[r]);
          ai[r] = fmaf(v.x, w.y, ai[r]); ai[r] = fmaf( v.y, w.x, ai[r]);
        }
      }
      idx += 20; m += dm; if (m >= OSZ) m -= OSZ;
    }
    #pragma unroll
    for (int r = 0; r < 8; ++r) A[r][k1 * 21 + n2] = make_float2(ar[r], ai[r]);
  }
  __syncthreads();

  if (tid < OSZ) {                            // stage 2, real part only
    int k = tid; int base = (k % 18) * 21;
    float xr[8];
    #pragma unroll
    for (int r = 0; r < 8; ++r) xr[r] = 0.f;
    int m = 0;
    #pragma unroll
    for (int n2 = 0; n2 < 20; ++n2) {
      float2 w = tw[m];
      #pragma unroll
      for (int r = 0; r < 8; ++r) {
        float2 a = A[r][base + n2];
        xr[r] = fmaf(a.x, w.x, xr[r]); xr[r] = fmaf(-a.y, w.y, xr[r]);
      }
      m += k; if (m >= OSZ) m -= OSZ;
    }
    int rowS = tid + HOSZ; if (rowS >= OSZ) rowS -= OSZ;   // baked fftshift
    int colS = kx  + HOSZ; if (colS >= OSZ) colS -= OSZ;
    float4* dst = (float4*)&KGs[((size_t)rowS * OSZ + colS) * CC + ch0];
    dst[0] = make_float4(xr[0], xr[1], xr[2], xr[3]);
    dst[1] = make_float4(xr[4], xr[5], xr[6], xr[7]);
  }
}

// ---------------------------------------------------------------------------
// Gridder: one thread per point p, all 16 channels. KGs is pre-fftshifted,
// so tap indices are plain mod-360. OUTPUT: float32 (C,P).
// ---------------------------------------------------------------------------
__global__ __launch_bounds__(256) void grid_points(
    const float* __restrict__ coord, const float* __restrict__ KGs,
    float* __restrict__ out) {
  int p = blockIdx.x * 256 + threadIdx.x;
  if (p >= PP) return;

  float2 cv = ((const float2*)coord)[p];
  float posy = __fadd_rn(__fmul_rn(cv.x, 1.125f), 180.0f);
  float posx = __fadd_rn(__fmul_rn(cv.y, 1.125f), 180.0f);
  float sty = ceilf(__fadd_rn(posy, -1.5f));
  float stx = ceilf(__fadd_rn(posx, -1.5f));

  float wy[3], wx[3];
  int jy[3], jx[3];
  #pragma unroll
  for (int r = 0; r < 3; ++r) {
    float gy = sty + (float)r;
    float dy = posy - gy;
    float xf = (2.0f * dy) / 3.0f;
    float arg = 1.0f - xf * xf;
    if (arg < 0.0f) arg = 0.0f;
    wy[r] = (fabsf(xf) <= 1.0f) ? i0f(BETA * sqrtf(arg)) : 0.0f;
    int gi = (int)gy;
    gi = gi % OSZ; if (gi < 0) gi += OSZ;
    jy[r] = gi;

    float gx = stx + (float)r;
    float dx = posx - gx;
    xf = (2.0f * dx) / 3.0f;
    arg = 1.0f - xf * xf;
    if (arg < 0.0f) arg = 0.0f;
    wx[r] = (fabsf(xf) <= 1.0f) ? i0f(BETA * sqrtf(arg)) : 0.0f;
    gi = (int)gx;
    gi = gi % OSZ; if (gi < 0) gi += OSZ;
    jx[r] = gi;
  }

  float acc[CC];
  #pragma unroll
  for (int c = 0; c < CC; ++c) acc[c] = 0.0f;

  #pragma unroll
  for (int a = 0; a < 3; ++a) {
    #pragma unroll
    for (int b = 0; b < 3; ++b) {
      float w = wy[a] * wx[b];
      const float4* g4 = (const float4*)(KGs + ((size_t)jy[a] * OSZ + jx[b]) * CC);
      #pragma unroll
      for (int h = 0; h < 4; ++h) {
        float4 v = g4[h];
        acc[4*h+0] = fmaf(w, v.x, acc[4*h+0]);
        acc[4*h+1] = fmaf(w, v.y, acc[4*h+1]);
        acc[4*h+2] = fmaf(w, v.z, acc[4*h+2]);
        acc[4*h+3] = fmaf(w, v.w, acc[4*h+3]);
      }
    }
  }

  #pragma unroll
  for (int c = 0; c < CC; ++c) out[(size_t)c * PP + p] = acc[c];
}

extern "C" void kernel_launch(void* const* d_in, const int* in_sizes, int n_in,
                              void* d_out, int out_size, void* d_ws, size_t ws_size,
                              hipStream_t stream) {
  bool sizes_ok = (n_in >= 3) &&
                  (in_sizes[0] == CC * NN * NN) &&
                  (in_sizes[1] == CC * NN * NN) &&
                  (in_sizes[2] == PP * 2);
  if (!sizes_ok) {
    hipLaunchKernelGGL(sentinel_kernel, dim3(1), dim3(64), 0, stream,
                       (float*)d_out, 555.0f);
    return;
  }
  if (ws_size < (size_t)CC * OSZ * OSZ * sizeof(float)) {  // 8,294,400 B
    hipLaunchKernelGGL(sentinel_kernel, dim3(1), dim3(64), 0, stream,
                       (float*)d_out, 777.0f);
    return;
  }

  const float* imr   = (const float*)d_in[0];
  const float* imi   = (const float*)d_in[1];
  const float* coord = (const float*)d_in[2];

  // d_out = 4,194,304 float32 = 16.78 MB (real part of kdata, (C,P)).
  // T1 scratch (complex float2, 16.59 MB) fits in d_out, dead before
  // grid_points overwrites all of d_out. KGs (real, 8.29 MB) in d_ws.
  float2* T1  = (float2*)d_out;
  float*  KGs = (float*)d_ws;

  hipLaunchKernelGGL(nufft_pass1, dim3(CC * (OSZ / QT)), dim3(384), 0, stream,
                     imr, imi, T1);
  hipLaunchKernelGGL(nufft_pass2, dim3(OSZ * 2), dim3(384), 0, stream,
                     T1, KGs);
  hipLaunchKernelGGL(grid_points, dim3(PP / 256), dim3(256), 0, stream,
                     coord, KGs, (float*)d_out);
}

// Round 13
// 79.658 us; speedup vs baseline: 5.9256x; 1.1997x over previous
//
#include <hip/hip_runtime.h>
#include <math.h>

#define NN    320
#define CC    16
#define PP    262144
#define OSZ   360
#define HOSZ  180
#define BETA  4.4180974f
#define BETA2 19.5195850f
#define PIW_OS 0.02617993878f                 // pi*W/OS = pi/120
#define RAD_PER 0.017453292519943295f         // 2*pi/360
#define QT 8                                  // q-rows per pass1 block

// ---------- Kaiser-Bessel I0 (A&S 9.8.1 / 9.8.2, rel err ~2e-7) ----------
__device__ __forceinline__ float i0f(float x) {
  if (x < 3.75f) {
    float t = x * (1.0f / 3.75f); t *= t;
    return 1.0f + t*(3.5156229f + t*(3.0899424f + t*(1.2067492f +
           t*(0.2659732f + t*(0.0360768f + t*0.0045813f)))));
  } else {
    float t = 3.75f / x;
    float p = 0.39894228f + t*(0.01328592f + t*(0.00225319f + t*(-0.00157565f +
              t*(0.00916281f + t*(-0.02057706f + t*(0.02635537f +
              t*(-0.01647633f + t*0.00392377f)))))));
    return p * expf(x) * rsqrtf(x);
  }
}

// image-domain apodization a[i], i in [0,320)
__device__ __forceinline__ float apodf(int i) {
  float u = PIW_OS * (float)(i - 160);
  float t2 = BETA2 - u * u;
  float t = sqrtf(fmaxf(t2, 1e-12f));
  return t / sinhf(t);
}

// Sentinel: fill first 64 output floats with a marker value (diagnostic).
__global__ void sentinel_kernel(float* out, float v) {
  if (threadIdx.x < 64) out[threadIdx.x] = v;
}

// ---------------------------------------------------------------------------
// Two-stage Cooley-Tukey 360 = 18 x 20, batched 8 rows per barrier phase.
// stage2 twiddles by in-register recurrence (kills the n2*k bank-conflicted
// tw gather; drift ~1e-6 rel over 20 steps, invisible vs threshold).
// ---------------------------------------------------------------------------

// Pass 1: block = (c, 8-row q-tile). 3 barriers per block.
__global__ __launch_bounds__(384) void nufft_pass1(
    const float* __restrict__ imr, const float* __restrict__ imi,
    float2* __restrict__ T1) {
  int bid = blockIdx.x;
  int c  = bid / (OSZ / QT);                 // 45 tiles per channel
  int qt = bid - c * (OSZ / QT);
  int q0 = qt * QT;
  int tid = threadIdx.x;

  __shared__ float2 tw[OSZ];
  __shared__ float  apodL[NN];
  __shared__ float2 srow[QT][OSZ];
  __shared__ float2 A[QT][18 * 21];

  for (int n = tid; n < OSZ; n += 384) {
    float sn, cs; sincosf(-RAD_PER * (float)n, &sn, &cs);
    tw[n] = make_float2(cs, sn);
  }
  for (int i = tid; i < NN; i += 384) apodL[i] = apodf(i);

  // fully-zero q-tile fast path (q in [160,200) are pad rows)
  if (q0 >= 160 && q0 + QT <= 200) {
    if (tid < OSZ) {
      float4 z = make_float4(0.f, 0.f, 0.f, 0.f);
      float4* dst = (float4*)&T1[((size_t)(c * OSZ + tid)) * OSZ + q0];
      dst[0] = z; dst[1] = z; dst[2] = z; dst[3] = z;
    }
    return;
  }
  __syncthreads();                            // apodL ready

  // load all 8 apodized/padded/ifftshifted rows
  const float inv360 = 1.0f / 360.0f;
  for (int i = tid; i < QT * OSZ; i += 384) {
    int r = i / OSZ, n = i - r * OSZ;
    int q = q0 + r;
    int y = (q + 180) % OSZ - 20;
    int x = (n + 180) % OSZ - 20;
    float2 v = make_float2(0.0f, 0.0f);
    if (y >= 0 && y < NN && x >= 0 && x < NN) {
      float s = apodL[x] * (apodL[y] * inv360);
      size_t o = (size_t)(c * NN + y) * NN + x;
      v = make_float2(imr[o] * s, imi[o] * s);
    }
    srow[r][n] = v;
  }
  __syncthreads();

  if (tid < OSZ) {                            // stage 1, all 8 rows
    int k1 = tid / 20, n2 = tid - k1 * 20;
    int dm = 20 * k1;                         // <= 340, single-wrap safe
    float ar[QT], ai[QT];
    #pragma unroll
    for (int r = 0; r < QT; ++r) { ar[r] = 0.f; ai[r] = 0.f; }
    int m = 0, idx = n2;
    #pragma unroll
    for (int n1 = 0; n1 < 18; ++n1) {
      if (n1 != 8 && n1 != 9) {               // n1=8,9: pad band, exact zeros
        float2 w = tw[m];                     // uniform per 20-lane group
        #pragma unroll
        for (int r = 0; r < QT; ++r) {
          float2 v = srow[r][idx];
          ar[r] = fmaf(v.x, w.x, ar[r]); ar[r] = fmaf(-v.y, w.y, ar[r]);
          ai[r] = fmaf(v.x, w.y, ai[r]); ai[r] = fmaf( v.y, w.x, ai[r]);
        }
      }
      idx += 20; m += dm; if (m >= OSZ) m -= OSZ;
    }
    #pragma unroll
    for (int r = 0; r < QT; ++r) A[r][k1 * 21 + n2] = make_float2(ar[r], ai[r]);
  }
  __syncthreads();

  if (tid < OSZ) {                            // stage 2: register twiddles
    int k = tid; int base = (k % 18) * 21;
    float2 step = tw[k];
    float wr = 1.0f, wi = 0.0f;
    float xr[QT], xi[QT];
    #pragma unroll
    for (int r = 0; r < QT; ++r) { xr[r] = 0.f; xi[r] = 0.f; }
    #pragma unroll
    for (int n2 = 0; n2 < 20; ++n2) {
      #pragma unroll
      for (int r = 0; r < QT; ++r) {
        float2 a = A[r][base + n2];
        xr[r] = fmaf(a.x, wr, xr[r]); xr[r] = fmaf(-a.y, wi, xr[r]);
        xi[r] = fmaf(a.x, wi, xi[r]); xi[r] = fmaf( a.y, wr, xi[r]);
      }
      float nwr = fmaf(wr, step.x, -wi * step.y);
      float nwi = fmaf(wr, step.y,  wi * step.x);
      wr = nwr; wi = nwi;
    }
    float4* dst = (float4*)&T1[((size_t)(c * OSZ + tid)) * OSZ + q0];
    dst[0] = make_float4(xr[0], xi[0], xr[1], xi[1]);
    dst[1] = make_float4(xr[2], xi[2], xr[3], xi[3]);
    dst[2] = make_float4(xr[4], xi[4], xr[5], xi[5]);
    dst[3] = make_float4(xr[6], xi[6], xr[7], xi[7]);
  }
}

// Pass 2: block = (kx, 8-channel group). 2 barriers per block.
// Writes KGs PRE-FFTSHIFTED: KGs[(k+180)%360][(kx+180)%360][c] = Re F[k][kx].
__global__ __launch_bounds__(384) void nufft_pass2(
    const float2* __restrict__ T1, float* __restrict__ KGs) {
  int bid = blockIdx.x;
  int kx  = bid >> 1;
  int ch0 = (bid & 1) * 8;
  int tid = threadIdx.x;

  __shared__ float2 tw[OSZ];
  __shared__ float2 srow[8][OSZ];
  __shared__ float2 A[8][18 * 21];

  for (int n = tid; n < OSZ; n += 384) {
    float sn, cs; sincosf(-RAD_PER * (float)n, &sn, &cs);
    tw[n] = make_float2(cs, sn);
  }
  // load 8 channels' q-columns (T1 rows zero for q in [160,200): skip read)
  for (int i = tid; i < 8 * OSZ; i += 384) {
    int ci = i / OSZ, n = i - ci * OSZ;
    float2 v = make_float2(0.0f, 0.0f);
    if (n < 160 || n >= 200)
      v = T1[((size_t)((ch0 + ci) * OSZ + kx)) * OSZ + n];
    srow[ci][n] = v;
  }
  __syncthreads();

  if (tid < OSZ) {                            // stage 1, all 8 channels
    int k1 = tid / 20, n2 = tid - k1 * 20;
    int dm = 20 * k1;
    float ar[8], ai[8];
    #pragma unroll
    for (int r = 0; r < 8; ++r) { ar[r] = 0.f; ai[r] = 0.f; }
    int m = 0, idx = n2;
    #pragma unroll
    for (int n1 = 0; n1 < 18; ++n1) {
      if (n1 != 8 && n1 != 9) {               // q pad band, exact zeros
        float2 w = tw[m];
        #pragma unroll
        for (int r = 0; r < 8; ++r) {
          float2 v = srow[r][idx];
          ar[r] = fmaf(v.x, w.x, ar[r]); ar[r] = fmaf(-v.y, w.y, ar[r]);
          ai[r] = fmaf(v.x, w.y, ai[r]); ai[r] = fmaf( v.y, w.x, ai[r]);
        }
      }
      idx += 20; m += dm; if (m >= OSZ) m -= OSZ;
    }
    #pragma unroll
    for (int r = 0; r < 8; ++r) A[r][k1 * 21 + n2] = make_float2(ar[r], ai[r]);
  }
  __syncthreads();

  if (tid < OSZ) {                            // stage 2: register twiddles, Re only
    int k = tid; int base = (k % 18) * 21;
    float2 step = tw[k];
    float wr = 1.0f, wi = 0.0f;
    float xr[8];
    #pragma unroll
    for (int r = 0; r < 8; ++r) xr[r] = 0.f;
    #pragma unroll
    for (int n2 = 0; n2 < 20; ++n2) {
      #pragma unroll
      for (int r = 0; r < 8; ++r) {
        float2 a = A[r][base + n2];
        xr[r] = fmaf(a.x, wr, xr[r]); xr[r] = fmaf(-a.y, wi, xr[r]);
      }
      float nwr = fmaf(wr, step.x, -wi * step.y);
      float nwi = fmaf(wr, step.y,  wi * step.x);
      wr = nwr; wi = nwi;
    }
    int rowS = tid + HOSZ; if (rowS >= OSZ) rowS -= OSZ;   // baked fftshift
    int colS = kx  + HOSZ; if (colS >= OSZ) colS -= OSZ;
    float4* dst = (float4*)&KGs[((size_t)rowS * OSZ + colS) * CC + ch0];
    dst[0] = make_float4(xr[0], xr[1], xr[2], xr[3]);
    dst[1] = make_float4(xr[4], xr[5], xr[6], xr[7]);
  }
}

// ---------------------------------------------------------------------------
// Gridder v3: FOUR lanes per point (q = g&3), each lane owns one float4
// (4 channels) of the 64B channel-cell -> lanes 4i..4i+3 hit the SAME cache
// line per tap (1 line-touch per point per tap, the data minimum; v2 had 4x
// amplification). Weights recomputed per lane (~4us VALU total, acceptable).
// KGs is pre-fftshifted; taps are plain mod-360. OUTPUT: float32 (C,P).
// ---------------------------------------------------------------------------
__global__ __launch_bounds__(256) void grid_points4(
    const float* __restrict__ coord, const float* __restrict__ KGs,
    float* __restrict__ out) {
  int g = blockIdx.x * 256 + threadIdx.x;     // g = p*4 + q
  int p = g >> 2;
  int q = g & 3;
  if (p >= PP) return;

  float2 cv = ((const float2*)coord)[p];
  float posy = __fadd_rn(__fmul_rn(cv.x, 1.125f), 180.0f);
  float posx = __fadd_rn(__fmul_rn(cv.y, 1.125f), 180.0f);
  float sty = ceilf(__fadd_rn(posy, -1.5f));
  float stx = ceilf(__fadd_rn(posx, -1.5f));

  float wy[3], wx[3];
  int jy[3], jx[3];
  #pragma unroll
  for (int r = 0; r < 3; ++r) {
    float gy = sty + (float)r;
    float dy = posy - gy;
    float xf = (2.0f * dy) / 3.0f;
    float arg = 1.0f - xf * xf;
    if (arg < 0.0f) arg = 0.0f;
    wy[r] = (fabsf(xf) <= 1.0f) ? i0f(BETA * sqrtf(arg)) : 0.0f;
    int gi = (int)gy;
    gi = gi % OSZ; if (gi < 0) gi += OSZ;
    jy[r] = gi;

    float gx = stx + (float)r;
    float dx = posx - gx;
    xf = (2.0f * dx) / 3.0f;
    arg = 1.0f - xf * xf;
    if (arg < 0.0f) arg = 0.0f;
    wx[r] = (fabsf(xf) <= 1.0f) ? i0f(BETA * sqrtf(arg)) : 0.0f;
    gi = (int)gx;
    gi = gi % OSZ; if (gi < 0) gi += OSZ;
    jx[r] = gi;
  }

  float4 acc = make_float4(0.f, 0.f, 0.f, 0.f);
  #pragma unroll
  for (int a = 0; a < 3; ++a) {
    #pragma unroll
    for (int b = 0; b < 3; ++b) {
      float w = wy[a] * wx[b];
      const float4* cell = (const float4*)(KGs + ((size_t)jy[a] * OSZ + jx[b]) * CC);
      float4 v = cell[q];
      acc.x = fmaf(w, v.x, acc.x);
      acc.y = fmaf(w, v.y, acc.y);
      acc.z = fmaf(w, v.z, acc.z);
      acc.w = fmaf(w, v.w, acc.w);
    }
  }

  int c0 = q * 4;
  out[(size_t)(c0 + 0) * PP + p] = acc.x;
  out[(size_t)(c0 + 1) * PP + p] = acc.y;
  out[(size_t)(c0 + 2) * PP + p] = acc.z;
  out[(size_t)(c0 + 3) * PP + p] = acc.w;
}

extern "C" void kernel_launch(void* const* d_in, const int* in_sizes, int n_in,
                              void* d_out, int out_size, void* d_ws, size_t ws_size,
                              hipStream_t stream) {
  bool sizes_ok = (n_in >= 3) &&
                  (in_sizes[0] == CC * NN * NN) &&
                  (in_sizes[1] == CC * NN * NN) &&
                  (in_sizes[2] == PP * 2);
  if (!sizes_ok) {
    hipLaunchKernelGGL(sentinel_kernel, dim3(1), dim3(64), 0, stream,
                       (float*)d_out, 555.0f);
    return;
  }
  if (ws_size < (size_t)CC * OSZ * OSZ * sizeof(float)) {  // 8,294,400 B
    hipLaunchKernelGGL(sentinel_kernel, dim3(1), dim3(64), 0, stream,
                       (float*)d_out, 777.0f);
    return;
  }

  const float* imr   = (const float*)d_in[0];
  const float* imi   = (const float*)d_in[1];
  const float* coord = (const float*)d_in[2];

  // d_out = 4,194,304 float32 = 16.78 MB (real part of kdata, (C,P)).
  // T1 scratch (complex float2, 16.59 MB) fits in d_out, dead before
  // grid_points4 overwrites all of d_out. KGs (real, 8.29 MB) in d_ws.
  float2* T1  = (float2*)d_out;
  float*  KGs = (float*)d_ws;

  hipLaunchKernelGGL(nufft_pass1, dim3(CC * (OSZ / QT)), dim3(384), 0, stream,
                     imr, imi, T1);
  hipLaunchKernelGGL(nufft_pass2, dim3(OSZ * 2), dim3(384), 0, stream,
                     T1, KGs);
  hipLaunchKernelGGL(grid_points4, dim3((PP * 4) / 256), dim3(256), 0, stream,
                     coord, KGs, (float*)d_out);
}

// Round 14
// 66.773 us; speedup vs baseline: 7.0690x; 1.1930x over previous
//
#include <hip/hip_runtime.h>
#include <math.h>

#define NN    320
#define CC    16
#define PP    262144
#define OSZ   360
#define HOSZ  180
#define BETA  4.4180974f
#define BETA2 19.5195850f
#define PIW_OS 0.02617993878f                 // pi*W/OS = pi/120
#define RAD_PER 0.017453292519943295f         // 2*pi/360
#define QT 4                                  // q-rows per pass1 block

// ---------- Kaiser-Bessel I0 (A&S 9.8.1 / 9.8.2, rel err ~2e-7) ----------
__device__ __forceinline__ float i0f(float x) {
  if (x < 3.75f) {
    float t = x * (1.0f / 3.75f); t *= t;
    return 1.0f + t*(3.5156229f + t*(3.0899424f + t*(1.2067492f +
           t*(0.2659732f + t*(0.0360768f + t*0.0045813f)))));
  } else {
    float t = 3.75f / x;
    float p = 0.39894228f + t*(0.01328592f + t*(0.00225319f + t*(-0.00157565f +
              t*(0.00916281f + t*(-0.02057706f + t*(0.02635537f +
              t*(-0.01647633f + t*0.00392377f)))))));
    return p * expf(x) * rsqrtf(x);
  }
}

// image-domain apodization a[i], i in [0,320)
__device__ __forceinline__ float apodf(int i) {
  float u = PIW_OS * (float)(i - 160);
  float t2 = BETA2 - u * u;
  float t = sqrtf(fmaxf(t2, 1e-12f));
  return t / sinhf(t);
}

// bf16 round-to-nearest-even (low 16 bits hold the bf16)
__device__ __forceinline__ unsigned int f2bf(float f) {
  unsigned int u = __float_as_uint(f);
  return (u + 0x7FFFu + ((u >> 16) & 1u)) >> 16;
}

// Sentinel: fill first 64 output floats with a marker value (diagnostic).
__global__ void sentinel_kernel(float* out, float v) {
  if (threadIdx.x < 64) out[threadIdx.x] = v;
}

// ---------------------------------------------------------------------------
// Two-stage Cooley-Tukey 360 = 18 x 20. QT=4 rows/block (27.8 KB LDS ->
// 5 blocks/CU = 30 waves/CU, was 3/18 at QT=8 -> LDS latency now hidden).
// ---------------------------------------------------------------------------

// Pass 1: block = (c, 4-row q-tile). 3 barriers per block.
__global__ __launch_bounds__(384) void nufft_pass1(
    const float* __restrict__ imr, const float* __restrict__ imi,
    float2* __restrict__ T1) {
  int bid = blockIdx.x;
  int c  = bid / (OSZ / QT);                 // 90 tiles per channel
  int qt = bid - c * (OSZ / QT);
  int q0 = qt * QT;
  int tid = threadIdx.x;

  __shared__ float2 tw[OSZ];
  __shared__ float  apodL[NN];
  __shared__ float2 srow[QT][OSZ];
  __shared__ float2 A[QT][18 * 21];

  for (int n = tid; n < OSZ; n += 384) {
    float sn, cs; sincosf(-RAD_PER * (float)n, &sn, &cs);
    tw[n] = make_float2(cs, sn);
  }
  for (int i = tid; i < NN; i += 384) apodL[i] = apodf(i);

  // fully-zero q-tile fast path (q in [160,200) are pad rows)
  if (q0 >= 160 && q0 + QT <= 200) {
    if (tid < OSZ) {
      float4 z = make_float4(0.f, 0.f, 0.f, 0.f);
      float4* dst = (float4*)&T1[((size_t)(c * OSZ + tid)) * OSZ + q0];
      dst[0] = z; dst[1] = z;
    }
    return;
  }
  __syncthreads();                            // apodL ready

  // load the 4 apodized/padded/ifftshifted rows
  const float inv360 = 1.0f / 360.0f;
  for (int i = tid; i < QT * OSZ; i += 384) {
    int r = i / OSZ, n = i - r * OSZ;
    int q = q0 + r;
    int y = (q + 180) % OSZ - 20;
    int x = (n + 180) % OSZ - 20;
    float2 v = make_float2(0.0f, 0.0f);
    if (y >= 0 && y < NN && x >= 0 && x < NN) {
      float s = apodL[x] * (apodL[y] * inv360);
      size_t o = (size_t)(c * NN + y) * NN + x;
      v = make_float2(imr[o] * s, imi[o] * s);
    }
    srow[r][n] = v;
  }
  __syncthreads();

  if (tid < OSZ) {                            // stage 1, 4 rows
    int k1 = tid / 20, n2 = tid - k1 * 20;
    int dm = 20 * k1;                         // <= 340, single-wrap safe
    float ar[QT], ai[QT];
    #pragma unroll
    for (int r = 0; r < QT; ++r) { ar[r] = 0.f; ai[r] = 0.f; }
    int m = 0, idx = n2;
    #pragma unroll
    for (int n1 = 0; n1 < 18; ++n1) {
      if (n1 != 8 && n1 != 9) {               // n1=8,9: pad band, exact zeros
        float2 w = tw[m];
        #pragma unroll
        for (int r = 0; r < QT; ++r) {
          float2 v = srow[r][idx];
          ar[r] = fmaf(v.x, w.x, ar[r]); ar[r] = fmaf(-v.y, w.y, ar[r]);
          ai[r] = fmaf(v.x, w.y, ai[r]); ai[r] = fmaf( v.y, w.x, ai[r]);
        }
      }
      idx += 20; m += dm; if (m >= OSZ) m -= OSZ;
    }
    #pragma unroll
    for (int r = 0; r < QT; ++r) A[r][k1 * 21 + n2] = make_float2(ar[r], ai[r]);
  }
  __syncthreads();

  if (tid < OSZ) {                            // stage 2: register twiddles
    int k = tid; int base = (k % 18) * 21;
    float2 step = tw[k];
    float wr = 1.0f, wi = 0.0f;
    float xr[QT], xi[QT];
    #pragma unroll
    for (int r = 0; r < QT; ++r) { xr[r] = 0.f; xi[r] = 0.f; }
    #pragma unroll
    for (int n2 = 0; n2 < 20; ++n2) {
      #pragma unroll
      for (int r = 0; r < QT; ++r) {
        float2 a = A[r][base + n2];
        xr[r] = fmaf(a.x, wr, xr[r]); xr[r] = fmaf(-a.y, wi, xr[r]);
        xi[r] = fmaf(a.x, wi, xi[r]); xi[r] = fmaf( a.y, wr, xi[r]);
      }
      float nwr = fmaf(wr, step.x, -wi * step.y);
      float nwi = fmaf(wr, step.y,  wi * step.x);
      wr = nwr; wi = nwi;
    }
    float4* dst = (float4*)&T1[((size_t)(c * OSZ + tid)) * OSZ + q0];
    dst[0] = make_float4(xr[0], xi[0], xr[1], xi[1]);
    dst[1] = make_float4(xr[2], xi[2], xr[3], xi[3]);
  }
}

// Pass 2: block = (kx, 4-channel group), 1440 blocks. 2 barriers per block.
// Writes KGb (bf16, pre-fftshifted): KGb[(k+180)%360][(kx+180)%360][c].
__global__ __launch_bounds__(384) void nufft_pass2(
    const float2* __restrict__ T1, unsigned short* __restrict__ KGb) {
  int bid = blockIdx.x;
  int kx  = bid >> 2;
  int ch0 = (bid & 3) * 4;
  int tid = threadIdx.x;

  __shared__ float2 tw[OSZ];
  __shared__ float2 srow[4][OSZ];
  __shared__ float2 A[4][18 * 21];

  for (int n = tid; n < OSZ; n += 384) {
    float sn, cs; sincosf(-RAD_PER * (float)n, &sn, &cs);
    tw[n] = make_float2(cs, sn);
  }
  // load 4 channels' q-columns (T1 rows zero for q in [160,200): skip read)
  for (int i = tid; i < 4 * OSZ; i += 384) {
    int ci = i / OSZ, n = i - ci * OSZ;
    float2 v = make_float2(0.0f, 0.0f);
    if (n < 160 || n >= 200)
      v = T1[((size_t)((ch0 + ci) * OSZ + kx)) * OSZ + n];
    srow[ci][n] = v;
  }
  __syncthreads();

  if (tid < OSZ) {                            // stage 1, 4 channels
    int k1 = tid / 20, n2 = tid - k1 * 20;
    int dm = 20 * k1;
    float ar[4], ai[4];
    #pragma unroll
    for (int r = 0; r < 4; ++r) { ar[r] = 0.f; ai[r] = 0.f; }
    int m = 0, idx = n2;
    #pragma unroll
    for (int n1 = 0; n1 < 18; ++n1) {
      if (n1 != 8 && n1 != 9) {               // q pad band, exact zeros
        float2 w = tw[m];
        #pragma unroll
        for (int r = 0; r < 4; ++r) {
          float2 v = srow[r][idx];
          ar[r] = fmaf(v.x, w.x, ar[r]); ar[r] = fmaf(-v.y, w.y, ar[r]);
          ai[r] = fmaf(v.x, w.y, ai[r]); ai[r] = fmaf( v.y, w.x, ai[r]);
        }
      }
      idx += 20; m += dm; if (m >= OSZ) m -= OSZ;
    }
    #pragma unroll
    for (int r = 0; r < 4; ++r) A[r][k1 * 21 + n2] = make_float2(ar[r], ai[r]);
  }
  __syncthreads();

  if (tid < OSZ) {                            // stage 2: register twiddles, Re only
    int k = tid; int base = (k % 18) * 21;
    float2 step = tw[k];
    float wr = 1.0f, wi = 0.0f;
    float xr[4];
    #pragma unroll
    for (int r = 0; r < 4; ++r) xr[r] = 0.f;
    #pragma unroll
    for (int n2 = 0; n2 < 20; ++n2) {
      #pragma unroll
      for (int r = 0; r < 4; ++r) {
        float2 a = A[r][base + n2];
        xr[r] = fmaf(a.x, wr, xr[r]); xr[r] = fmaf(-a.y, wi, xr[r]);
      }
      float nwr = fmaf(wr, step.x, -wi * step.y);
      float nwi = fmaf(wr, step.y,  wi * step.x);
      wr = nwr; wi = nwi;
    }
    int rowS = tid + HOSZ; if (rowS >= OSZ) rowS -= OSZ;   // baked fftshift
    int colS = kx  + HOSZ; if (colS >= OSZ) colS -= OSZ;
    uint2 packed;
    packed.x = (f2bf(xr[1]) << 16) | f2bf(xr[0]);
    packed.y = (f2bf(xr[3]) << 16) | f2bf(xr[2]);
    uint2* dst = (uint2*)&KGb[((size_t)rowS * OSZ + colS) * CC + ch0];
    *dst = packed;
  }
}

// ---------------------------------------------------------------------------
// Gridder v4: TWO lanes per point (q = g&1); each lane loads 16B = 8 bf16
// channels of the 32B cell per tap. KGb = 4.15 MB (~per-XCD L2 capacity).
// OUTPUT: float32 (C,P).
// ---------------------------------------------------------------------------
__global__ __launch_bounds__(256) void grid_points2(
    const float* __restrict__ coord, const unsigned short* __restrict__ KGb,
    float* __restrict__ out) {
  int g = blockIdx.x * 256 + threadIdx.x;     // g = p*2 + q
  int p = g >> 1;
  int q = g & 1;
  if (p >= PP) return;

  float2 cv = ((const float2*)coord)[p];
  float posy = __fadd_rn(__fmul_rn(cv.x, 1.125f), 180.0f);
  float posx = __fadd_rn(__fmul_rn(cv.y, 1.125f), 180.0f);
  float sty = ceilf(__fadd_rn(posy, -1.5f));
  float stx = ceilf(__fadd_rn(posx, -1.5f));

  float wy[3], wx[3];
  int jy[3], jx[3];
  #pragma unroll
  for (int r = 0; r < 3; ++r) {
    float gy = sty + (float)r;
    float dy = posy - gy;
    float xf = (2.0f * dy) / 3.0f;
    float arg = 1.0f - xf * xf;
    if (arg < 0.0f) arg = 0.0f;
    wy[r] = (fabsf(xf) <= 1.0f) ? i0f(BETA * sqrtf(arg)) : 0.0f;
    int gi = (int)gy;
    gi = gi % OSZ; if (gi < 0) gi += OSZ;
    jy[r] = gi;

    float gx = stx + (float)r;
    float dx = posx - gx;
    xf = (2.0f * dx) / 3.0f;
    arg = 1.0f - xf * xf;
    if (arg < 0.0f) arg = 0.0f;
    wx[r] = (fabsf(xf) <= 1.0f) ? i0f(BETA * sqrtf(arg)) : 0.0f;
    gi = (int)gx;
    gi = gi % OSZ; if (gi < 0) gi += OSZ;
    jx[r] = gi;
  }

  float acc[8];
  #pragma unroll
  for (int j = 0; j < 8; ++j) acc[j] = 0.0f;

  #pragma unroll
  for (int a = 0; a < 3; ++a) {
    #pragma unroll
    for (int b = 0; b < 3; ++b) {
      float w = wy[a] * wx[b];
      const uint4* cell = (const uint4*)(KGb + ((size_t)jy[a] * OSZ + jx[b]) * CC);
      uint4 v = cell[q];                      // 8 bf16 channels
      acc[0] = fmaf(w, __uint_as_float(v.x << 16),          acc[0]);
      acc[1] = fmaf(w, __uint_as_float(v.x & 0xffff0000u),  acc[1]);
      acc[2] = fmaf(w, __uint_as_float(v.y << 16),          acc[2]);
      acc[3] = fmaf(w, __uint_as_float(v.y & 0xffff0000u),  acc[3]);
      acc[4] = fmaf(w, __uint_as_float(v.z << 16),          acc[4]);
      acc[5] = fmaf(w, __uint_as_float(v.z & 0xffff0000u),  acc[5]);
      acc[6] = fmaf(w, __uint_as_float(v.w << 16),          acc[6]);
      acc[7] = fmaf(w, __uint_as_float(v.w & 0xffff0000u),  acc[7]);
    }
  }

  int c0 = q * 8;
  #pragma unroll
  for (int j = 0; j < 8; ++j) out[(size_t)(c0 + j) * PP + p] = acc[j];
}

extern "C" void kernel_launch(void* const* d_in, const int* in_sizes, int n_in,
                              void* d_out, int out_size, void* d_ws, size_t ws_size,
                              hipStream_t stream) {
  bool sizes_ok = (n_in >= 3) &&
                  (in_sizes[0] == CC * NN * NN) &&
                  (in_sizes[1] == CC * NN * NN) &&
                  (in_sizes[2] == PP * 2);
  if (!sizes_ok) {
    hipLaunchKernelGGL(sentinel_kernel, dim3(1), dim3(64), 0, stream,
                       (float*)d_out, 555.0f);
    return;
  }
  if (ws_size < (size_t)CC * OSZ * OSZ * sizeof(unsigned short)) {  // 4,147,200 B
    hipLaunchKernelGGL(sentinel_kernel, dim3(1), dim3(64), 0, stream,
                       (float*)d_out, 777.0f);
    return;
  }

  const float* imr   = (const float*)d_in[0];
  const float* imi   = (const float*)d_in[1];
  const float* coord = (const float*)d_in[2];

  // d_out = 4,194,304 float32 = 16.78 MB (real part of kdata, (C,P)).
  // T1 scratch (complex float2, 16.59 MB) fits in d_out, dead before
  // grid_points2 overwrites all of d_out. KGb (bf16, 4.15 MB) in d_ws.
  float2* T1 = (float2*)d_out;
  unsigned short* KGb = (unsigned short*)d_ws;

  hipLaunchKernelGGL(nufft_pass1, dim3(CC * (OSZ / QT)), dim3(384), 0, stream,
                     imr, imi, T1);
  hipLaunchKernelGGL(nufft_pass2, dim3(OSZ * 4), dim3(384), 0, stream,
                     T1, KGb);
  hipLaunchKernelGGL(grid_points2, dim3((PP * 2) / 256), dim3(256), 0, stream,
                     coord, KGb, (float*)d_out);
}

// Round 15
// 66.110 us; speedup vs baseline: 7.1399x; 1.0100x over previous
//
#include <hip/hip_runtime.h>
#include <hip/hip_fp16.h>
#include <math.h>

#define NN    320
#define CC    16
#define PP    262144
#define OSZ   360
#define HOSZ  180
#define BETA2 19.519727f
#define PIW_OS 0.02617993878f                 // pi*W/OS = pi/120
#define RAD_PER 0.017453292519943295f         // 2*pi/360
#define QT 4                                  // q-rows per pass1 block

// image-domain apodization a[i], i in [0,320)
__device__ __forceinline__ float apodf(int i) {
  float u = PIW_OS * (float)(i - 160);
  float t2 = BETA2 - u * u;
  float t = sqrtf(fmaxf(t2, 1e-12f));
  return t / sinhf(t);
}

// bf16 round-to-nearest-even (result in low 16 bits)
__device__ __forceinline__ unsigned int f2bf(float f) {
  unsigned int u = __float_as_uint(f);
  return (u + 0x7FFFu + ((u >> 16) & 1u)) >> 16;
}

// Kaiser-Bessel weight, exact Taylor form: I0(beta*sqrt(arg)) =
// sum_m (beta^2/4)^m arg^m/(m!)^2 -- degree-12 Horner in arg (tail 2e-11).
// d in [-1.5,1.5] guaranteed -> |2d/3|<=1 branch is always true.
__device__ __forceinline__ float kbw(float d) {
  float xf = 0.66666667f * d;
  float h = fmaxf(fmaf(-xf, xf, 1.0f), 0.0f);   // arg = 1-(2d/3)^2, clipped
  float w =            7.948604e-10f;
  w = fmaf(w, h, 2.345522e-8f);
  w = fmaf(w, h, 5.815822e-7f);
  w = fmaf(w, h, 1.191783e-5f);
  w = fmaf(w, h, 1.978192e-4f);
  w = fmaf(w, h, 2.594386e-3f);
  w = fmaf(w, h, 2.605055e-2f);
  w = fmaf(w, h, 1.921789e-1f);
  w = fmaf(w, h, 9.845368e-1f);
  w = fmaf(w, h, 3.228036f);
  w = fmaf(w, h, 5.953434f);
  w = fmaf(w, h, 4.8799318f);
  w = fmaf(w, h, 1.0f);
  return w;
}

// Sentinel: fill first 64 output floats with a marker value (diagnostic).
__global__ void sentinel_kernel(float* out, float v) {
  if (threadIdx.x < 64) out[threadIdx.x] = v;
}

// ---------------------------------------------------------------------------
// Two-stage Cooley-Tukey 360 = 18 x 20. T1 now COMPLEX FP16 (half traffic).
// ---------------------------------------------------------------------------

// Pass 1: block = (c, 4-row q-tile). T1h[c][k][q] = one __half2 per complex.
__global__ __launch_bounds__(384) void nufft_pass1(
    const float* __restrict__ imr, const float* __restrict__ imi,
    __half2* __restrict__ T1h) {
  int bid = blockIdx.x;
  int c  = bid / (OSZ / QT);                 // 90 tiles per channel
  int qt = bid - c * (OSZ / QT);
  int q0 = qt * QT;
  int tid = threadIdx.x;

  __shared__ float2 tw[OSZ];
  __shared__ float  apodL[NN];
  __shared__ float2 srow[QT][OSZ];
  __shared__ float2 A[QT][18 * 21];

  for (int n = tid; n < OSZ; n += 384) {
    float sn, cs; sincosf(-RAD_PER * (float)n, &sn, &cs);
    tw[n] = make_float2(cs, sn);
  }
  for (int i = tid; i < NN; i += 384) apodL[i] = apodf(i);

  // fully-zero q-tile fast path (q in [160,200) are pad rows)
  if (q0 >= 160 && q0 + QT <= 200) {
    if (tid < OSZ) {
      uint2 z = make_uint2(0u, 0u);
      *(uint2*)&T1h[((size_t)(c * OSZ + tid)) * OSZ + q0] = z;
    }
    return;
  }
  __syncthreads();                            // apodL ready

  const float inv360 = 1.0f / 360.0f;
  for (int i = tid; i < QT * OSZ; i += 384) {
    int r = i / OSZ, n = i - r * OSZ;
    int q = q0 + r;
    int y = (q + 180) % OSZ - 20;
    int x = (n + 180) % OSZ - 20;
    float2 v = make_float2(0.0f, 0.0f);
    if (y >= 0 && y < NN && x >= 0 && x < NN) {
      float s = apodL[x] * (apodL[y] * inv360);
      size_t o = (size_t)(c * NN + y) * NN + x;
      v = make_float2(imr[o] * s, imi[o] * s);
    }
    srow[r][n] = v;
  }
  __syncthreads();

  if (tid < OSZ) {                            // stage 1, 4 rows
    int k1 = tid / 20, n2 = tid - k1 * 20;
    int dm = 20 * k1;                         // <= 340, single-wrap safe
    float ar[QT], ai[QT];
    #pragma unroll
    for (int r = 0; r < QT; ++r) { ar[r] = 0.f; ai[r] = 0.f; }
    int m = 0, idx = n2;
    #pragma unroll
    for (int n1 = 0; n1 < 18; ++n1) {
      if (n1 != 8 && n1 != 9) {               // n1=8,9: pad band, exact zeros
        float2 w = tw[m];
        #pragma unroll
        for (int r = 0; r < QT; ++r) {
          float2 v = srow[r][idx];
          ar[r] = fmaf(v.x, w.x, ar[r]); ar[r] = fmaf(-v.y, w.y, ar[r]);
          ai[r] = fmaf(v.x, w.y, ai[r]); ai[r] = fmaf( v.y, w.x, ai[r]);
        }
      }
      idx += 20; m += dm; if (m >= OSZ) m -= OSZ;
    }
    #pragma unroll
    for (int r = 0; r < QT; ++r) A[r][k1 * 21 + n2] = make_float2(ar[r], ai[r]);
  }
  __syncthreads();

  if (tid < OSZ) {                            // stage 2: register twiddles
    int k = tid; int base = (k % 18) * 21;
    float2 step = tw[k];
    float wr = 1.0f, wi = 0.0f;
    float xr[QT], xi[QT];
    #pragma unroll
    for (int r = 0; r < QT; ++r) { xr[r] = 0.f; xi[r] = 0.f; }
    #pragma unroll
    for (int n2 = 0; n2 < 20; ++n2) {
      #pragma unroll
      for (int r = 0; r < QT; ++r) {
        float2 a = A[r][base + n2];
        xr[r] = fmaf(a.x, wr, xr[r]); xr[r] = fmaf(-a.y, wi, xr[r]);
        xi[r] = fmaf(a.x, wi, xi[r]); xi[r] = fmaf( a.y, wr, xi[r]);
      }
      float nwr = fmaf(wr, step.x, -wi * step.y);
      float nwi = fmaf(wr, step.y,  wi * step.x);
      wr = nwr; wi = nwi;
    }
    __half2 h0 = __float22half2_rn(make_float2(xr[0], xi[0]));
    __half2 h1 = __float22half2_rn(make_float2(xr[1], xi[1]));
    __half2 h2 = __float22half2_rn(make_float2(xr[2], xi[2]));
    __half2 h3 = __float22half2_rn(make_float2(xr[3], xi[3]));
    uint4 pk = make_uint4(*(unsigned int*)&h0, *(unsigned int*)&h1,
                          *(unsigned int*)&h2, *(unsigned int*)&h3);
    *(uint4*)&T1h[((size_t)(c * OSZ + tid)) * OSZ + q0] = pk;
  }
}

// Pass 2: block = (kx, 4-channel group), 1440 blocks.
// Writes KGb (bf16, pre-fftshifted): KGb[(k+180)%360][(kx+180)%360][c].
__global__ __launch_bounds__(384) void nufft_pass2(
    const __half2* __restrict__ T1h, unsigned short* __restrict__ KGb) {
  int bid = blockIdx.x;
  int kx  = bid >> 2;
  int ch0 = (bid & 3) * 4;
  int tid = threadIdx.x;

  __shared__ float2 tw[OSZ];
  __shared__ float2 srow[4][OSZ];
  __shared__ float2 A[4][18 * 21];

  for (int n = tid; n < OSZ; n += 384) {
    float sn, cs; sincosf(-RAD_PER * (float)n, &sn, &cs);
    tw[n] = make_float2(cs, sn);
  }
  // load 4 channels' q-columns (T1 rows zero for q in [160,200): skip read)
  for (int i = tid; i < 4 * OSZ; i += 384) {
    int ci = i / OSZ, n = i - ci * OSZ;
    float2 v = make_float2(0.0f, 0.0f);
    if (n < 160 || n >= 200)
      v = __half22float2(T1h[((size_t)((ch0 + ci) * OSZ + kx)) * OSZ + n]);
    srow[ci][n] = v;
  }
  __syncthreads();

  if (tid < OSZ) {                            // stage 1, 4 channels
    int k1 = tid / 20, n2 = tid - k1 * 20;
    int dm = 20 * k1;
    float ar[4], ai[4];
    #pragma unroll
    for (int r = 0; r < 4; ++r) { ar[r] = 0.f; ai[r] = 0.f; }
    int m = 0, idx = n2;
    #pragma unroll
    for (int n1 = 0; n1 < 18; ++n1) {
      if (n1 != 8 && n1 != 9) {               // q pad band, exact zeros
        float2 w = tw[m];
        #pragma unroll
        for (int r = 0; r < 4; ++r) {
          float2 v = srow[r][idx];
          ar[r] = fmaf(v.x, w.x, ar[r]); ar[r] = fmaf(-v.y, w.y, ar[r]);
          ai[r] = fmaf(v.x, w.y, ai[r]); ai[r] = fmaf( v.y, w.x, ai[r]);
        }
      }
      idx += 20; m += dm; if (m >= OSZ) m -= OSZ;
    }
    #pragma unroll
    for (int r = 0; r < 4; ++r) A[r][k1 * 21 + n2] = make_float2(ar[r], ai[r]);
  }
  __syncthreads();

  if (tid < OSZ) {                            // stage 2: register twiddles, Re only
    int k = tid; int base = (k % 18) * 21;
    float2 step = tw[k];
    float wr = 1.0f, wi = 0.0f;
    float xr[4];
    #pragma unroll
    for (int r = 0; r < 4; ++r) xr[r] = 0.f;
    #pragma unroll
    for (int n2 = 0; n2 < 20; ++n2) {
      #pragma unroll
      for (int r = 0; r < 4; ++r) {
        float2 a = A[r][base + n2];
        xr[r] = fmaf(a.x, wr, xr[r]); xr[r] = fmaf(-a.y, wi, xr[r]);
      }
      float nwr = fmaf(wr, step.x, -wi * step.y);
      float nwi = fmaf(wr, step.y,  wi * step.x);
      wr = nwr; wi = nwi;
    }
    int rowS = tid + HOSZ; if (rowS >= OSZ) rowS -= OSZ;   // baked fftshift
    int colS = kx  + HOSZ; if (colS >= OSZ) colS -= OSZ;
    uint2 packed;
    packed.x = (f2bf(xr[1]) << 16) | f2bf(xr[0]);
    packed.y = (f2bf(xr[3]) << 16) | f2bf(xr[2]);
    *(uint2*)&KGb[((size_t)rowS * OSZ + colS) * CC + ch0] = packed;
  }
}

// ---------------------------------------------------------------------------
// Gridder v5: two lanes per point (q = g&1); 16B (8 bf16 channels) per tap
// per lane. Weights via branchless degree-12 Horner (no transcendentals).
// OUTPUT: float32 (C,P).
// ---------------------------------------------------------------------------
__global__ __launch_bounds__(256) void grid_points2(
    const float* __restrict__ coord, const unsigned short* __restrict__ KGb,
    float* __restrict__ out) {
  int g = blockIdx.x * 256 + threadIdx.x;     // g = p*2 + q
  int p = g >> 1;
  int q = g & 1;
  if (p >= PP) return;

  float2 cv = ((const float2*)coord)[p];
  float posy = __fadd_rn(__fmul_rn(cv.x, 1.125f), 180.0f);
  float posx = __fadd_rn(__fmul_rn(cv.y, 1.125f), 180.0f);
  float sty = ceilf(__fadd_rn(posy, -1.5f));
  float stx = ceilf(__fadd_rn(posx, -1.5f));

  float wy[3], wx[3];
  int jy[3], jx[3];
  #pragma unroll
  for (int r = 0; r < 3; ++r) {
    float gy = sty + (float)r;
    wy[r] = kbw(posy - gy);
    int gi = (int)gy;                          // gi in [-1,360]
    if (gi < 0) gi += OSZ;
    if (gi >= OSZ) gi -= OSZ;
    jy[r] = gi;

    float gx = stx + (float)r;
    wx[r] = kbw(posx - gx);
    gi = (int)gx;
    if (gi < 0) gi += OSZ;
    if (gi >= OSZ) gi -= OSZ;
    jx[r] = gi;
  }

  float acc[8];
  #pragma unroll
  for (int j = 0; j < 8; ++j) acc[j] = 0.0f;

  #pragma unroll
  for (int a = 0; a < 3; ++a) {
    #pragma unroll
    for (int b = 0; b < 3; ++b) {
      float w = wy[a] * wx[b];
      const uint4* cell = (const uint4*)(KGb + ((size_t)jy[a] * OSZ + jx[b]) * CC);
      uint4 v = cell[q];                      // 8 bf16 channels
      acc[0] = fmaf(w, __uint_as_float(v.x << 16),          acc[0]);
      acc[1] = fmaf(w, __uint_as_float(v.x & 0xffff0000u),  acc[1]);
      acc[2] = fmaf(w, __uint_as_float(v.y << 16),          acc[2]);
      acc[3] = fmaf(w, __uint_as_float(v.y & 0xffff0000u),  acc[3]);
      acc[4] = fmaf(w, __uint_as_float(v.z << 16),          acc[4]);
      acc[5] = fmaf(w, __uint_as_float(v.z & 0xffff0000u),  acc[5]);
      acc[6] = fmaf(w, __uint_as_float(v.w << 16),          acc[6]);
      acc[7] = fmaf(w, __uint_as_float(v.w & 0xffff0000u),  acc[7]);
    }
  }

  int c0 = q * 8;
  #pragma unroll
  for (int j = 0; j < 8; ++j) out[(size_t)(c0 + j) * PP + p] = acc[j];
}

extern "C" void kernel_launch(void* const* d_in, const int* in_sizes, int n_in,
                              void* d_out, int out_size, void* d_ws, size_t ws_size,
                              hipStream_t stream) {
  bool sizes_ok = (n_in >= 3) &&
                  (in_sizes[0] == CC * NN * NN) &&
                  (in_sizes[1] == CC * NN * NN) &&
                  (in_sizes[2] == PP * 2);
  if (!sizes_ok) {
    hipLaunchKernelGGL(sentinel_kernel, dim3(1), dim3(64), 0, stream,
                       (float*)d_out, 555.0f);
    return;
  }
  if (ws_size < (size_t)CC * OSZ * OSZ * sizeof(unsigned short)) {  // 4,147,200 B
    hipLaunchKernelGGL(sentinel_kernel, dim3(1), dim3(64), 0, stream,
                       (float*)d_out, 777.0f);
    return;
  }

  const float* imr   = (const float*)d_in[0];
  const float* imi   = (const float*)d_in[1];
  const float* coord = (const float*)d_in[2];

  // d_out = 4,194,304 float32 = 16.78 MB (real part of kdata, (C,P)).
  // T1h scratch (complex fp16, 8.29 MB) fits in d_out, dead before
  // grid_points2 overwrites all of d_out. KGb (bf16, 4.15 MB) in d_ws.
  __half2* T1h = (__half2*)d_out;
  unsigned short* KGb = (unsigned short*)d_ws;

  hipLaunchKernelGGL(nufft_pass1, dim3(CC * (OSZ / QT)), dim3(384), 0, stream,
                     imr, imi, T1h);
  hipLaunchKernelGGL(nufft_pass2, dim3(OSZ * 4), dim3(384), 0, stream,
                     T1h, KGb);
  hipLaunchKernelGGL(grid_points2, dim3((PP * 2) / 256), dim3(256), 0, stream,
                     coord, KGb, (float*)d_out);
}

// Round 16
// 63.460 us; speedup vs baseline: 7.4381x; 1.0418x over previous
//
#include <hip/hip_runtime.h>
#include <hip/hip_fp16.h>
#include <math.h>

#define NN    320
#define CC    16
#define PP    262144
#define OSZ   360
#define HOSZ  180
#define BETA2 19.519727f
#define PIW_OS 0.02617993878f                 // pi*W/OS = pi/120
#define RAD_PER 0.017453292519943295f         // 2*pi/360
#define QT 8                                  // q-rows per pass1 block

// image-domain apodization a[i], i in [0,320)
__device__ __forceinline__ float apodf(int i) {
  float u = PIW_OS * (float)(i - 160);
  float t2 = BETA2 - u * u;
  float t = sqrtf(fmaxf(t2, 1e-12f));
  return t / sinhf(t);
}

// bf16 round-to-nearest-even (result in low 16 bits)
__device__ __forceinline__ unsigned int f2bf(float f) {
  unsigned int u = __float_as_uint(f);
  return (u + 0x7FFFu + ((u >> 16) & 1u)) >> 16;
}

// Kaiser-Bessel weight: degree-12 Horner in arg = 1-(2d/3)^2 (exact Taylor
// of I0(beta*sqrt(arg)); tail 2e-11). d in [-1.5,1.5] -> branchless.
__device__ __forceinline__ float kbw(float d) {
  float xf = 0.66666667f * d;
  float h = fmaxf(fmaf(-xf, xf, 1.0f), 0.0f);
  float w =            7.948604e-10f;
  w = fmaf(w, h, 2.345522e-8f);
  w = fmaf(w, h, 5.815822e-7f);
  w = fmaf(w, h, 1.191783e-5f);
  w = fmaf(w, h, 1.978192e-4f);
  w = fmaf(w, h, 2.594386e-3f);
  w = fmaf(w, h, 2.605055e-2f);
  w = fmaf(w, h, 1.921789e-1f);
  w = fmaf(w, h, 9.845368e-1f);
  w = fmaf(w, h, 3.228036f);
  w = fmaf(w, h, 5.953434f);
  w = fmaf(w, h, 4.8799318f);
  w = fmaf(w, h, 1.0f);
  return w;
}

// Sentinel: fill first 64 output floats with a marker value (diagnostic).
__global__ void sentinel_kernel(float* out, float v) {
  if (threadIdx.x < 64) out[threadIdx.x] = v;
}

// ---------------------------------------------------------------------------
// Two-stage Cooley-Tukey 360 = 18 x 20 with k/k+180 PARITY PAIRING:
//   180 % 18 == 0  ->  k and k+180 share the stage-2 A row; twiddles differ
//   by exactly (-1)^{n2} (and k1/k1+9 in stage 1 by (-1)^{n1}).
//   One thread computes BOTH outputs from ONE set of LDS reads -> block-wide
//   LDS read traffic halves at unchanged FMA count. Sign flips are exact.
// Block layout: 384 threads; tid<180 -> rows 0-3, tid in [192,372) -> rows
// 4-7 (QT=8 rows per block, 720 blocks, ~single resident cohort at 3/CU).
// ---------------------------------------------------------------------------

// Pass 1: block = (c, 8-row q-tile). T1h[c][k][q] = one __half2 per complex.
__global__ __launch_bounds__(384) void nufft_pass1(
    const float* __restrict__ imr, const float* __restrict__ imi,
    __half2* __restrict__ T1h) {
  int bid = blockIdx.x;
  int c  = bid / (OSZ / QT);                 // 45 tiles per channel
  int qt = bid - c * (OSZ / QT);
  int q0 = qt * QT;
  int tid = threadIdx.x;

  __shared__ float2 tw[OSZ];
  __shared__ float  apodL[NN];
  __shared__ float2 srow[QT][OSZ];
  __shared__ float2 A[QT][18 * 21];

  for (int n = tid; n < OSZ; n += 384) {
    float sn, cs; sincosf(-RAD_PER * (float)n, &sn, &cs);
    tw[n] = make_float2(cs, sn);
  }
  for (int i = tid; i < NN; i += 384) apodL[i] = apodf(i);

  // fully-zero q-tile fast path (q in [160,200) are pad rows)
  if (q0 >= 160 && q0 + QT <= 200) {
    if (tid < OSZ) {
      uint4 z = make_uint4(0u, 0u, 0u, 0u);
      uint4* dst = (uint4*)&T1h[((size_t)(c * OSZ + tid)) * OSZ + q0];
      dst[0] = z; dst[1] = z;
    }
    return;
  }
  __syncthreads();                            // apodL ready

  const float inv360 = 1.0f / 360.0f;
  for (int i = tid; i < QT * OSZ; i += 384) {
    int r = i / OSZ, n = i - r * OSZ;
    int q = q0 + r;
    int y = (q + 180) % OSZ - 20;
    int x = (n + 180) % OSZ - 20;
    float2 v = make_float2(0.0f, 0.0f);
    if (y >= 0 && y < NN && x >= 0 && x < NN) {
      float s = apodL[x] * (apodL[y] * inv360);
      size_t o = (size_t)(c * NN + y) * NN + x;
      v = make_float2(imr[o] * s, imi[o] * s);
    }
    srow[r][n] = v;
  }
  __syncthreads();

  int half = (tid >= 192) ? 1 : 0;
  int t = tid - 192 * half;                   // 0..191
  int r0 = half * 4;

  if (t < 180) {                              // stage 1: k1 and k1+9 paired
    int k1 = t / 20, n2 = t - k1 * 20;        // k1 in 0..8
    int dm = 20 * k1;
    float arA[4], aiA[4], arB[4], aiB[4];
    #pragma unroll
    for (int r = 0; r < 4; ++r) { arA[r]=0.f; aiA[r]=0.f; arB[r]=0.f; aiB[r]=0.f; }
    int m = 0, idx = n2;
    #pragma unroll
    for (int n1 = 0; n1 < 18; ++n1) {
      if (n1 != 8 && n1 != 9) {               // pad band: exact zeros
        float2 w = tw[m];
        float sx = (n1 & 1) ? -w.x : w.x;     // (-1)^{n1} tw[m] == tw for k1+9
        float sy = (n1 & 1) ? -w.y : w.y;
        #pragma unroll
        for (int r = 0; r < 4; ++r) {
          float2 v = srow[r0 + r][idx];
          arA[r] = fmaf(v.x, w.x, arA[r]); arA[r] = fmaf(-v.y, w.y, arA[r]);
          aiA[r] = fmaf(v.x, w.y, aiA[r]); aiA[r] = fmaf( v.y, w.x, aiA[r]);
          arB[r] = fmaf(v.x, sx,  arB[r]); arB[r] = fmaf(-v.y, sy,  arB[r]);
          aiB[r] = fmaf(v.x, sy,  aiB[r]); aiB[r] = fmaf( v.y, sx,  aiB[r]);
        }
      }
      idx += 20; m += dm; if (m >= OSZ) m -= OSZ;
    }
    #pragma unroll
    for (int r = 0; r < 4; ++r) {
      A[r0 + r][k1 * 21 + n2]       = make_float2(arA[r], aiA[r]);
      A[r0 + r][(k1 + 9) * 21 + n2] = make_float2(arB[r], aiB[r]);
    }
  }
  __syncthreads();

  if (t < 180) {                              // stage 2: k and k+180 paired
    int k = t;
    int base = (k % 18) * 21;                 // shared by k and k+180
    float2 step = tw[k];
    float wr = 1.0f, wi = 0.0f;
    float xrA[4], xiA[4], xrB[4], xiB[4];
    #pragma unroll
    for (int r = 0; r < 4; ++r) { xrA[r]=0.f; xiA[r]=0.f; xrB[r]=0.f; xiB[r]=0.f; }
    #pragma unroll
    for (int n2 = 0; n2 < 20; ++n2) {
      float sbr = (n2 & 1) ? -wr : wr;        // (-1)^{n2} w == twiddle of k+180
      float sbi = (n2 & 1) ? -wi : wi;
      #pragma unroll
      for (int r = 0; r < 4; ++r) {
        float2 a = A[r0 + r][base + n2];
        xrA[r] = fmaf(a.x, wr,  xrA[r]); xrA[r] = fmaf(-a.y, wi,  xrA[r]);
        xiA[r] = fmaf(a.x, wi,  xiA[r]); xiA[r] = fmaf( a.y, wr,  xiA[r]);
        xrB[r] = fmaf(a.x, sbr, xrB[r]); xrB[r] = fmaf(-a.y, sbi, xrB[r]);
        xiB[r] = fmaf(a.x, sbi, xiB[r]); xiB[r] = fmaf( a.y, sbr, xiB[r]);
      }
      float nwr = fmaf(wr, step.x, -wi * step.y);
      float nwi = fmaf(wr, step.y,  wi * step.x);
      wr = nwr; wi = nwi;
    }
    __half2 a0 = __float22half2_rn(make_float2(xrA[0], xiA[0]));
    __half2 a1 = __float22half2_rn(make_float2(xrA[1], xiA[1]));
    __half2 a2 = __float22half2_rn(make_float2(xrA[2], xiA[2]));
    __half2 a3 = __float22half2_rn(make_float2(xrA[3], xiA[3]));
    uint4 pkA = make_uint4(*(unsigned int*)&a0, *(unsigned int*)&a1,
                           *(unsigned int*)&a2, *(unsigned int*)&a3);
    *(uint4*)&T1h[((size_t)(c * OSZ + k)) * OSZ + q0 + r0] = pkA;
    __half2 b0 = __float22half2_rn(make_float2(xrB[0], xiB[0]));
    __half2 b1 = __float22half2_rn(make_float2(xrB[1], xiB[1]));
    __half2 b2 = __float22half2_rn(make_float2(xrB[2], xiB[2]));
    __half2 b3 = __float22half2_rn(make_float2(xrB[3], xiB[3]));
    uint4 pkB = make_uint4(*(unsigned int*)&b0, *(unsigned int*)&b1,
                           *(unsigned int*)&b2, *(unsigned int*)&b3);
    *(uint4*)&T1h[((size_t)(c * OSZ + k + HOSZ)) * OSZ + q0 + r0] = pkB;
  }
}

// Pass 2: block = (kx, 8-channel group), 720 blocks. Parity-paired stages.
// Writes KGb (bf16, pre-fftshifted): KGb[(k+180)%360][(kx+180)%360][c].
__global__ __launch_bounds__(384) void nufft_pass2(
    const __half2* __restrict__ T1h, unsigned short* __restrict__ KGb) {
  int bid = blockIdx.x;
  int kx  = bid >> 1;
  int chb = (bid & 1) * 8;
  int tid = threadIdx.x;

  __shared__ float2 tw[OSZ];
  __shared__ float2 srow[8][OSZ];
  __shared__ float2 A[8][18 * 21];

  for (int n = tid; n < OSZ; n += 384) {
    float sn, cs; sincosf(-RAD_PER * (float)n, &sn, &cs);
    tw[n] = make_float2(cs, sn);
  }
  // load 8 channels' q-columns (T1 rows zero for q in [160,200): skip read)
  for (int i = tid; i < 8 * OSZ; i += 384) {
    int ci = i / OSZ, n = i - ci * OSZ;
    float2 v = make_float2(0.0f, 0.0f);
    if (n < 160 || n >= 200)
      v = __half22float2(T1h[((size_t)((chb + ci) * OSZ + kx)) * OSZ + n]);
    srow[ci][n] = v;
  }
  __syncthreads();

  int half = (tid >= 192) ? 1 : 0;
  int t = tid - 192 * half;
  int r0 = half * 4;                          // channel sub-base

  if (t < 180) {                              // stage 1: k1 / k1+9 paired
    int k1 = t / 20, n2 = t - k1 * 20;
    int dm = 20 * k1;
    float arA[4], aiA[4], arB[4], aiB[4];
    #pragma unroll
    for (int r = 0; r < 4; ++r) { arA[r]=0.f; aiA[r]=0.f; arB[r]=0.f; aiB[r]=0.f; }
    int m = 0, idx = n2;
    #pragma unroll
    for (int n1 = 0; n1 < 18; ++n1) {
      if (n1 != 8 && n1 != 9) {               // q pad band, exact zeros
        float2 w = tw[m];
        float sx = (n1 & 1) ? -w.x : w.x;
        float sy = (n1 & 1) ? -w.y : w.y;
        #pragma unroll
        for (int r = 0; r < 4; ++r) {
          float2 v = srow[r0 + r][idx];
          arA[r] = fmaf(v.x, w.x, arA[r]); arA[r] = fmaf(-v.y, w.y, arA[r]);
          aiA[r] = fmaf(v.x, w.y, aiA[r]); aiA[r] = fmaf( v.y, w.x, aiA[r]);
          arB[r] = fmaf(v.x, sx,  arB[r]); arB[r] = fmaf(-v.y, sy,  arB[r]);
          aiB[r] = fmaf(v.x, sy,  aiB[r]); aiB[r] = fmaf( v.y, sx,  aiB[r]);
        }
      }
      idx += 20; m += dm; if (m >= OSZ) m -= OSZ;
    }
    #pragma unroll
    for (int r = 0; r < 4; ++r) {
      A[r0 + r][k1 * 21 + n2]       = make_float2(arA[r], aiA[r]);
      A[r0 + r][(k1 + 9) * 21 + n2] = make_float2(arB[r], aiB[r]);
    }
  }
  __syncthreads();

  if (t < 180) {                              // stage 2: k / k+180, Re only
    int k = t;
    int base = (k % 18) * 21;
    float2 step = tw[k];
    float wr = 1.0f, wi = 0.0f;
    float xrA[4], xrB[4];
    #pragma unroll
    for (int r = 0; r < 4; ++r) { xrA[r] = 0.f; xrB[r] = 0.f; }
    #pragma unroll
    for (int n2 = 0; n2 < 20; ++n2) {
      float sbr = (n2 & 1) ? -wr : wr;
      float sbi = (n2 & 1) ? -wi : wi;
      #pragma unroll
      for (int r = 0; r < 4; ++r) {
        float2 a = A[r0 + r][base + n2];
        xrA[r] = fmaf(a.x, wr,  xrA[r]); xrA[r] = fmaf(-a.y, wi,  xrA[r]);
        xrB[r] = fmaf(a.x, sbr, xrB[r]); xrB[r] = fmaf(-a.y, sbi, xrB[r]);
      }
      float nwr = fmaf(wr, step.x, -wi * step.y);
      float nwi = fmaf(wr, step.y,  wi * step.x);
      wr = nwr; wi = nwi;
    }
    int colS = kx + HOSZ; if (colS >= OSZ) colS -= OSZ;
    // k = t      -> shifted row t+180 ; k+180 -> shifted row t
    uint2 pkA, pkB;
    pkA.x = (f2bf(xrA[1]) << 16) | f2bf(xrA[0]);
    pkA.y = (f2bf(xrA[3]) << 16) | f2bf(xrA[2]);
    pkB.x = (f2bf(xrB[1]) << 16) | f2bf(xrB[0]);
    pkB.y = (f2bf(xrB[3]) << 16) | f2bf(xrB[2]);
    *(uint2*)&KGb[((size_t)(t + HOSZ) * OSZ + colS) * CC + chb + r0] = pkA;
    *(uint2*)&KGb[((size_t)t * OSZ + colS) * CC + chb + r0]          = pkB;
  }
}

// ---------------------------------------------------------------------------
// Gridder v5 (unchanged from round 15): two lanes per point; 16B (8 bf16
// channels) per tap per lane; branchless polynomial KB weights.
// OUTPUT: float32 (C,P).
// ---------------------------------------------------------------------------
__global__ __launch_bounds__(256) void grid_points2(
    const float* __restrict__ coord, const unsigned short* __restrict__ KGb,
    float* __restrict__ out) {
  int g = blockIdx.x * 256 + threadIdx.x;     // g = p*2 + q
  int p = g >> 1;
  int q = g & 1;
  if (p >= PP) return;

  float2 cv = ((const float2*)coord)[p];
  float posy = __fadd_rn(__fmul_rn(cv.x, 1.125f), 180.0f);
  float posx = __fadd_rn(__fmul_rn(cv.y, 1.125f), 180.0f);
  float sty = ceilf(__fadd_rn(posy, -1.5f));
  float stx = ceilf(__fadd_rn(posx, -1.5f));

  float wy[3], wx[3];
  int jy[3], jx[3];
  #pragma unroll
  for (int r = 0; r < 3; ++r) {
    float gy = sty + (float)r;
    wy[r] = kbw(posy - gy);
    int gi = (int)gy;                          // gi in [-1,360]
    if (gi < 0) gi += OSZ;
    if (gi >= OSZ) gi -= OSZ;
    jy[r] = gi;

    float gx = stx + (float)r;
    wx[r] = kbw(posx - gx);
    gi = (int)gx;
    if (gi < 0) gi += OSZ;
    if (gi >= OSZ) gi -= OSZ;
    jx[r] = gi;
  }

  float acc[8];
  #pragma unroll
  for (int j = 0; j < 8; ++j) acc[j] = 0.0f;

  #pragma unroll
  for (int a = 0; a < 3; ++a) {
    #pragma unroll
    for (int b = 0; b < 3; ++b) {
      float w = wy[a] * wx[b];
      const uint4* cell = (const uint4*)(KGb + ((size_t)jy[a] * OSZ + jx[b]) * CC);
      uint4 v = cell[q];                      // 8 bf16 channels
      acc[0] = fmaf(w, __uint_as_float(v.x << 16),          acc[0]);
      acc[1] = fmaf(w, __uint_as_float(v.x & 0xffff0000u),  acc[1]);
      acc[2] = fmaf(w, __uint_as_float(v.y << 16),          acc[2]);
      acc[3] = fmaf(w, __uint_as_float(v.y & 0xffff0000u),  acc[3]);
      acc[4] = fmaf(w, __uint_as_float(v.z << 16),          acc[4]);
      acc[5] = fmaf(w, __uint_as_float(v.z & 0xffff0000u),  acc[5]);
      acc[6] = fmaf(w, __uint_as_float(v.w << 16),          acc[6]);
      acc[7] = fmaf(w, __uint_as_float(v.w & 0xffff0000u),  acc[7]);
    }
  }

  int c0 = q * 8;
  #pragma unroll
  for (int j = 0; j < 8; ++j) out[(size_t)(c0 + j) * PP + p] = acc[j];
}

extern "C" void kernel_launch(void* const* d_in, const int* in_sizes, int n_in,
                              void* d_out, int out_size, void* d_ws, size_t ws_size,
                              hipStream_t stream) {
  bool sizes_ok = (n_in >= 3) &&
                  (in_sizes[0] == CC * NN * NN) &&
                  (in_sizes[1] == CC * NN * NN) &&
                  (in_sizes[2] == PP * 2);
  if (!sizes_ok) {
    hipLaunchKernelGGL(sentinel_kernel, dim3(1), dim3(64), 0, stream,
                       (float*)d_out, 555.0f);
    return;
  }
  if (ws_size < (size_t)CC * OSZ * OSZ * sizeof(unsigned short)) {  // 4,147,200 B
    hipLaunchKernelGGL(sentinel_kernel, dim3(1), dim3(64), 0, stream,
                       (float*)d_out, 777.0f);
    return;
  }

  const float* imr   = (const float*)d_in[0];
  const float* imi   = (const float*)d_in[1];
  const float* coord = (const float*)d_in[2];

  // d_out = 4,194,304 float32 = 16.78 MB (real part of kdata, (C,P)).
  // T1h scratch (complex fp16, 8.29 MB) fits in d_out, dead before
  // grid_points2 overwrites all of d_out. KGb (bf16, 4.15 MB) in d_ws.
  __half2* T1h = (__half2*)d_out;
  unsigned short* KGb = (unsigned short*)d_ws;

  hipLaunchKernelGGL(nufft_pass1, dim3(CC * (OSZ / QT)), dim3(384), 0, stream,
                     imr, imi, T1h);
  hipLaunchKernelGGL(nufft_pass2, dim3(OSZ * 2), dim3(384), 0, stream,
                     T1h, KGb);
  hipLaunchKernelGGL(grid_points2, dim3((PP * 2) / 256), dim3(256), 0, stream,
                     coord, KGb, (float*)d_out);
}

// Round 17
// 58.580 us; speedup vs baseline: 8.0577x; 1.0833x over previous
//
#include <hip/hip_runtime.h>
#include <hip/hip_fp16.h>
#include <math.h>

#define NN    320
#define CC    16
#define PP    262144
#define OSZ   360
#define HOSZ  180
#define BETA2 19.519727f
#define PIW_OS 0.02617993878f                 // pi*W/OS = pi/120
#define RAD_PER 0.017453292519943295f         // 2*pi/360

// image-domain apodization a[i], i in [0,320)
__device__ __forceinline__ float apodf(int i) {
  float u = PIW_OS * (float)(i - 160);
  float t2 = BETA2 - u * u;
  float t = sqrtf(fmaxf(t2, 1e-12f));
  return t / sinhf(t);
}

// bf16 round-to-nearest-even (result in low 16 bits)
__device__ __forceinline__ unsigned int f2bf(float f) {
  unsigned int u = __float_as_uint(f);
  return (u + 0x7FFFu + ((u >> 16) & 1u)) >> 16;
}

// Kaiser-Bessel weight: degree-12 Horner in arg = 1-(2d/3)^2 (exact Taylor
// of I0(beta*sqrt(arg)); tail 2e-11). d in [-1.5,1.5] -> branchless.
__device__ __forceinline__ float kbw(float d) {
  float xf = 0.66666667f * d;
  float h = fmaxf(fmaf(-xf, xf, 1.0f), 0.0f);
  float w =            7.948604e-10f;
  w = fmaf(w, h, 2.345522e-8f);
  w = fmaf(w, h, 5.815822e-7f);
  w = fmaf(w, h, 1.191783e-5f);
  w = fmaf(w, h, 1.978192e-4f);
  w = fmaf(w, h, 2.594386e-3f);
  w = fmaf(w, h, 2.605055e-2f);
  w = fmaf(w, h, 1.921789e-1f);
  w = fmaf(w, h, 9.845368e-1f);
  w = fmaf(w, h, 3.228036f);
  w = fmaf(w, h, 5.953434f);
  w = fmaf(w, h, 4.8799318f);
  w = fmaf(w, h, 1.0f);
  return w;
}

// Sentinel: fill first 64 output floats with a marker value (diagnostic).
__global__ void sentinel_kernel(float* out, float v) {
  if (threadIdx.x < 64) out[threadIdx.x] = v;
}

// ---------------------------------------------------------------------------
// Two-stage Cooley-Tukey 360 = 18 x 20, k/k+180 parity-paired (r16 algebra,
// bit-identical). NEW: QT=2 rows per block, 192 threads -> 2880 small blocks,
// 15.6 KB LDS, ~10 blocks/CU -> block-latency hidden by block-level overlap
// (the r16 structure was a single 3-blocks/CU cohort = duration ~ one block's
// critical path).
// ---------------------------------------------------------------------------

// Pass 1: block = (c, 2-row q-tile). T1h[c][k][q] = one __half2 per complex.
__global__ __launch_bounds__(192) void nufft_pass1(
    const float* __restrict__ imr, const float* __restrict__ imi,
    __half2* __restrict__ T1h) {
  int bid = blockIdx.x;
  int c  = bid / 180;                        // 180 tiles per channel
  int qt = bid - c * 180;
  int q0 = qt * 2;
  int tid = threadIdx.x;

  __shared__ float2 tw[OSZ];
  __shared__ float  apodL[NN];
  __shared__ float2 srow[2][OSZ];
  __shared__ float2 A[2][18 * 21];

  for (int n = tid; n < OSZ; n += 192) {
    float sn, cs; sincosf(-RAD_PER * (float)n, &sn, &cs);
    tw[n] = make_float2(cs, sn);
  }
  for (int i = tid; i < NN; i += 192) apodL[i] = apodf(i);

  // fully-zero q-tile fast path (q in [160,200) are pad rows; boundaries
  // 160/200 are even so no tile straddles)
  if (q0 >= 160 && q0 < 200) {
    if (tid < OSZ)
      *(uint2*)&T1h[((size_t)(c * OSZ + tid)) * OSZ + q0] = make_uint2(0u, 0u);
    return;
  }
  __syncthreads();                            // apodL ready

  const float inv360 = 1.0f / 360.0f;
  for (int i = tid; i < 2 * OSZ; i += 192) {
    int r = i / OSZ, n = i - r * OSZ;
    int q = q0 + r;
    int y = (q + 180) % OSZ - 20;
    int x = (n + 180) % OSZ - 20;
    float2 v = make_float2(0.0f, 0.0f);
    if (y >= 0 && y < NN && x >= 0 && x < NN) {
      float s = apodL[x] * (apodL[y] * inv360);
      size_t o = (size_t)(c * NN + y) * NN + x;
      v = make_float2(imr[o] * s, imi[o] * s);
    }
    srow[r][n] = v;
  }
  __syncthreads();

  if (tid < 180) {                            // stage 1: k1 / k1+9 paired
    int k1 = tid / 20, n2 = tid - k1 * 20;    // k1 in 0..8
    int dm = 20 * k1;
    float arA[2], aiA[2], arB[2], aiB[2];
    #pragma unroll
    for (int r = 0; r < 2; ++r) { arA[r]=0.f; aiA[r]=0.f; arB[r]=0.f; aiB[r]=0.f; }
    int m = 0, idx = n2;
    #pragma unroll
    for (int n1 = 0; n1 < 18; ++n1) {
      if (n1 != 8 && n1 != 9) {               // pad band: exact zeros
        float2 w = tw[m];
        float sx = (n1 & 1) ? -w.x : w.x;     // (-1)^{n1} tw == tw for k1+9
        float sy = (n1 & 1) ? -w.y : w.y;
        #pragma unroll
        for (int r = 0; r < 2; ++r) {
          float2 v = srow[r][idx];
          arA[r] = fmaf(v.x, w.x, arA[r]); arA[r] = fmaf(-v.y, w.y, arA[r]);
          aiA[r] = fmaf(v.x, w.y, aiA[r]); aiA[r] = fmaf( v.y, w.x, aiA[r]);
          arB[r] = fmaf(v.x, sx,  arB[r]); arB[r] = fmaf(-v.y, sy,  arB[r]);
          aiB[r] = fmaf(v.x, sy,  aiB[r]); aiB[r] = fmaf( v.y, sx,  aiB[r]);
        }
      }
      idx += 20; m += dm; if (m >= OSZ) m -= OSZ;
    }
    #pragma unroll
    for (int r = 0; r < 2; ++r) {
      A[r][k1 * 21 + n2]       = make_float2(arA[r], aiA[r]);
      A[r][(k1 + 9) * 21 + n2] = make_float2(arB[r], aiB[r]);
    }
  }
  __syncthreads();

  if (tid < 180) {                            // stage 2: k / k+180 paired
    int k = tid;
    int base = (k % 18) * 21;                 // shared by k and k+180
    float2 step = tw[k];
    float wr = 1.0f, wi = 0.0f;
    float xrA[2], xiA[2], xrB[2], xiB[2];
    #pragma unroll
    for (int r = 0; r < 2; ++r) { xrA[r]=0.f; xiA[r]=0.f; xrB[r]=0.f; xiB[r]=0.f; }
    #pragma unroll
    for (int n2 = 0; n2 < 20; ++n2) {
      float sbr = (n2 & 1) ? -wr : wr;        // (-1)^{n2} w == twiddle of k+180
      float sbi = (n2 & 1) ? -wi : wi;
      #pragma unroll
      for (int r = 0; r < 2; ++r) {
        float2 a = A[r][base + n2];
        xrA[r] = fmaf(a.x, wr,  xrA[r]); xrA[r] = fmaf(-a.y, wi,  xrA[r]);
        xiA[r] = fmaf(a.x, wi,  xiA[r]); xiA[r] = fmaf( a.y, wr,  xiA[r]);
        xrB[r] = fmaf(a.x, sbr, xrB[r]); xrB[r] = fmaf(-a.y, sbi, xrB[r]);
        xiB[r] = fmaf(a.x, sbi, xiB[r]); xiB[r] = fmaf( a.y, sbr, xiB[r]);
      }
      float nwr = fmaf(wr, step.x, -wi * step.y);
      float nwi = fmaf(wr, step.y,  wi * step.x);
      wr = nwr; wi = nwi;
    }
    __half2 a0 = __float22half2_rn(make_float2(xrA[0], xiA[0]));
    __half2 a1 = __float22half2_rn(make_float2(xrA[1], xiA[1]));
    *(uint2*)&T1h[((size_t)(c * OSZ + k)) * OSZ + q0] =
        make_uint2(*(unsigned int*)&a0, *(unsigned int*)&a1);
    __half2 b0 = __float22half2_rn(make_float2(xrB[0], xiB[0]));
    __half2 b1 = __float22half2_rn(make_float2(xrB[1], xiB[1]));
    *(uint2*)&T1h[((size_t)(c * OSZ + k + HOSZ)) * OSZ + q0] =
        make_uint2(*(unsigned int*)&b0, *(unsigned int*)&b1);
  }
}

// Pass 2: block = (kx, 2-channel group), 2880 blocks. Parity-paired stages.
// Writes KGb (bf16, pre-fftshifted): KGb[(k+180)%360][(kx+180)%360][c].
__global__ __launch_bounds__(192) void nufft_pass2(
    const __half2* __restrict__ T1h, unsigned short* __restrict__ KGb) {
  int bid = blockIdx.x;
  int kx  = bid >> 3;
  int ch0 = (bid & 7) * 2;
  int tid = threadIdx.x;

  __shared__ float2 tw[OSZ];
  __shared__ float2 srow[2][OSZ];
  __shared__ float2 A[2][18 * 21];

  for (int n = tid; n < OSZ; n += 192) {
    float sn, cs; sincosf(-RAD_PER * (float)n, &sn, &cs);
    tw[n] = make_float2(cs, sn);
  }
  // load 2 channels' q-columns (T1 rows zero for q in [160,200): skip read)
  for (int i = tid; i < 2 * OSZ; i += 192) {
    int ci = i / OSZ, n = i - ci * OSZ;
    float2 v = make_float2(0.0f, 0.0f);
    if (n < 160 || n >= 200)
      v = __half22float2(T1h[((size_t)((ch0 + ci) * OSZ + kx)) * OSZ + n]);
    srow[ci][n] = v;
  }
  __syncthreads();

  if (tid < 180) {                            // stage 1: k1 / k1+9 paired
    int k1 = tid / 20, n2 = tid - k1 * 20;
    int dm = 20 * k1;
    float arA[2], aiA[2], arB[2], aiB[2];
    #pragma unroll
    for (int r = 0; r < 2; ++r) { arA[r]=0.f; aiA[r]=0.f; arB[r]=0.f; aiB[r]=0.f; }
    int m = 0, idx = n2;
    #pragma unroll
    for (int n1 = 0; n1 < 18; ++n1) {
      if (n1 != 8 && n1 != 9) {               // q pad band, exact zeros
        float2 w = tw[m];
        float sx = (n1 & 1) ? -w.x : w.x;
        float sy = (n1 & 1) ? -w.y : w.y;
        #pragma unroll
        for (int r = 0; r < 2; ++r) {
          float2 v = srow[r][idx];
          arA[r] = fmaf(v.x, w.x, arA[r]); arA[r] = fmaf(-v.y, w.y, arA[r]);
          aiA[r] = fmaf(v.x, w.y, aiA[r]); aiA[r] = fmaf( v.y, w.x, aiA[r]);
          arB[r] = fmaf(v.x, sx,  arB[r]); arB[r] = fmaf(-v.y, sy,  arB[r]);
          aiB[r] = fmaf(v.x, sy,  aiB[r]); aiB[r] = fmaf( v.y, sx,  aiB[r]);
        }
      }
      idx += 20; m += dm; if (m >= OSZ) m -= OSZ;
    }
    #pragma unroll
    for (int r = 0; r < 2; ++r) {
      A[r][k1 * 21 + n2]       = make_float2(arA[r], aiA[r]);
      A[r][(k1 + 9) * 21 + n2] = make_float2(arB[r], aiB[r]);
    }
  }
  __syncthreads();

  if (tid < 180) {                            // stage 2: k / k+180, Re only
    int k = tid;
    int base = (k % 18) * 21;
    float2 step = tw[k];
    float wr = 1.0f, wi = 0.0f;
    float xrA[2], xrB[2];
    #pragma unroll
    for (int r = 0; r < 2; ++r) { xrA[r] = 0.f; xrB[r] = 0.f; }
    #pragma unroll
    for (int n2 = 0; n2 < 20; ++n2) {
      float sbr = (n2 & 1) ? -wr : wr;
      float sbi = (n2 & 1) ? -wi : wi;
      #pragma unroll
      for (int r = 0; r < 2; ++r) {
        float2 a = A[r][base + n2];
        xrA[r] = fmaf(a.x, wr,  xrA[r]); xrA[r] = fmaf(-a.y, wi,  xrA[r]);
        xrB[r] = fmaf(a.x, sbr, xrB[r]); xrB[r] = fmaf(-a.y, sbi, xrB[r]);
      }
      float nwr = fmaf(wr, step.x, -wi * step.y);
      float nwi = fmaf(wr, step.y,  wi * step.x);
      wr = nwr; wi = nwi;
    }
    int colS = kx + HOSZ; if (colS >= OSZ) colS -= OSZ;
    // k = tid -> shifted row tid+180 ; k+180 -> shifted row tid
    unsigned int pkA = (f2bf(xrA[1]) << 16) | f2bf(xrA[0]);
    unsigned int pkB = (f2bf(xrB[1]) << 16) | f2bf(xrB[0]);
    *(unsigned int*)&KGb[((size_t)(tid + HOSZ) * OSZ + colS) * CC + ch0] = pkA;
    *(unsigned int*)&KGb[((size_t)tid * OSZ + colS) * CC + ch0]          = pkB;
  }
}

// ---------------------------------------------------------------------------
// Gridder v5 (unchanged): two lanes per point; 16B (8 bf16 channels) per tap
// per lane; branchless polynomial KB weights. OUTPUT: float32 (C,P).
// ---------------------------------------------------------------------------
__global__ __launch_bounds__(256) void grid_points2(
    const float* __restrict__ coord, const unsigned short* __restrict__ KGb,
    float* __restrict__ out) {
  int g = blockIdx.x * 256 + threadIdx.x;     // g = p*2 + q
  int p = g >> 1;
  int q = g & 1;
  if (p >= PP) return;

  float2 cv = ((const float2*)coord)[p];
  float posy = __fadd_rn(__fmul_rn(cv.x, 1.125f), 180.0f);
  float posx = __fadd_rn(__fmul_rn(cv.y, 1.125f), 180.0f);
  float sty = ceilf(__fadd_rn(posy, -1.5f));
  float stx = ceilf(__fadd_rn(posx, -1.5f));

  float wy[3], wx[3];
  int jy[3], jx[3];
  #pragma unroll
  for (int r = 0; r < 3; ++r) {
    float gy = sty + (float)r;
    wy[r] = kbw(posy - gy);
    int gi = (int)gy;                          // gi in [-1,360]
    if (gi < 0) gi += OSZ;
    if (gi >= OSZ) gi -= OSZ;
    jy[r] = gi;

    float gx = stx + (float)r;
    wx[r] = kbw(posx - gx);
    gi = (int)gx;
    if (gi < 0) gi += OSZ;
    if (gi >= OSZ) gi -= OSZ;
    jx[r] = gi;
  }

  float acc[8];
  #pragma unroll
  for (int j = 0; j < 8; ++j) acc[j] = 0.0f;

  #pragma unroll
  for (int a = 0; a < 3; ++a) {
    #pragma unroll
    for (int b = 0; b < 3; ++b) {
      float w = wy[a] * wx[b];
      const uint4* cell = (const uint4*)(KGb + ((size_t)jy[a] * OSZ + jx[b]) * CC);
      uint4 v = cell[q];                      // 8 bf16 channels
      acc[0] = fmaf(w, __uint_as_float(v.x << 16),          acc[0]);
      acc[1] = fmaf(w, __uint_as_float(v.x & 0xffff0000u),  acc[1]);
      acc[2] = fmaf(w, __uint_as_float(v.y << 16),          acc[2]);
      acc[3] = fmaf(w, __uint_as_float(v.y & 0xffff0000u),  acc[3]);
      acc[4] = fmaf(w, __uint_as_float(v.z << 16),          acc[4]);
      acc[5] = fmaf(w, __uint_as_float(v.z & 0xffff0000u),  acc[5]);
      acc[6] = fmaf(w, __uint_as_float(v.w << 16),          acc[6]);
      acc[7] = fmaf(w, __uint_as_float(v.w & 0xffff0000u),  acc[7]);
    }
  }

  int c0 = q * 8;
  #pragma unroll
  for (int j = 0; j < 8; ++j) out[(size_t)(c0 + j) * PP + p] = acc[j];
}

extern "C" void kernel_launch(void* const* d_in, const int* in_sizes, int n_in,
                              void* d_out, int out_size, void* d_ws, size_t ws_size,
                              hipStream_t stream) {
  bool sizes_ok = (n_in >= 3) &&
                  (in_sizes[0] == CC * NN * NN) &&
                  (in_sizes[1] == CC * NN * NN) &&
                  (in_sizes[2] == PP * 2);
  if (!sizes_ok) {
    hipLaunchKernelGGL(sentinel_kernel, dim3(1), dim3(64), 0, stream,
                       (float*)d_out, 555.0f);
    return;
  }
  if (ws_size < (size_t)CC * OSZ * OSZ * sizeof(unsigned short)) {  // 4,147,200 B
    hipLaunchKernelGGL(sentinel_kernel, dim3(1), dim3(64), 0, stream,
                       (float*)d_out, 777.0f);
    return;
  }

  const float* imr   = (const float*)d_in[0];
  const float* imi   = (const float*)d_in[1];
  const float* coord = (const float*)d_in[2];

  // d_out = 4,194,304 float32 = 16.78 MB (real part of kdata, (C,P)).
  // T1h scratch (complex fp16, 8.29 MB) fits in d_out, dead before
  // grid_points2 overwrites all of d_out. KGb (bf16, 4.15 MB) in d_ws.
  __half2* T1h = (__half2*)d_out;
  unsigned short* KGb = (unsigned short*)d_ws;

  hipLaunchKernelGGL(nufft_pass1, dim3(CC * 180), dim3(192), 0, stream,
                     imr, imi, T1h);
  hipLaunchKernelGGL(nufft_pass2, dim3(OSZ * 8), dim3(192), 0, stream,
                     T1h, KGb);
  hipLaunchKernelGGL(grid_points2, dim3((PP * 2) / 256), dim3(256), 0, stream,
                     coord, KGb, (float*)d_out);
}